// Round 1
// baseline (1185.376 us; speedup 1.0000x reference)
//
#include <hip/hip_runtime.h>
#include <hip/hip_bf16.h>

typedef __bf16 bf16;
typedef bf16 bf16x8 __attribute__((ext_vector_type(8)));
typedef float f32x4 __attribute__((ext_vector_type(4)));

struct alignas(8) bh4 { bf16 v[4]; };

// async global->LDS, 16B per lane. LDS dest must be wave-uniform base + lane*16.
__device__ __forceinline__ void glds16(const bf16* g, bf16* l) {
  __builtin_amdgcn_global_load_lds(
      (const __attribute__((address_space(1))) void*)g,
      (__attribute__((address_space(3))) void*)l, 16, 0, 0);
}

// log2(e) / sqrt(128): folded into Q so softmax uses exp2 (native v_exp_f32)
#define QSCALE (1.4426950408889634f / 11.313708498984761f)
// defer-max threshold (log2 domain): skip O-rescale while tile max grows <= 8.
// P values then bounded by 2^8=256 — safe in bf16/f32 accum (HK THR=8 regime).
#define DEFER_THR 8.0f

// fp32 -> bf16 conversion (inputs are fp32; established round 2).
__global__ void convert_to_bf16(const float* __restrict__ s, bf16* __restrict__ dst,
                                long n) {
  const long stride = (long)gridDim.x * blockDim.x * 8;
  for (long i = ((long)blockIdx.x * blockDim.x + threadIdx.x) * 8; i < n; i += stride) {
    float4 a = *(const float4*)(s + i);
    float4 b = *(const float4*)(s + i + 4);
    bf16x8 o;
    o[0] = (bf16)a.x; o[1] = (bf16)a.y; o[2] = (bf16)a.z; o[3] = (bf16)a.w;
    o[4] = (bf16)b.x; o[5] = (bf16)b.y; o[6] = (bf16)b.z; o[7] = (bf16)b.w;
    *(bf16x8*)(dst + i) = o;
  }
}

// ---------------- GEMM: C = A (M,K) * Bw^T, Bw is (N,K) row-major ----------
// 128x128 tile, BK=32, 4 waves 2x2 (verified round 3).
template <int MODE>
__global__ void gemm_bt(const bf16* __restrict__ A, const bf16* __restrict__ Bw,
                        void* __restrict__ C0v, bf16* __restrict__ C1,
                        bf16* __restrict__ C2, int M, int N, int K) {
  __shared__ __align__(16) bf16 sA[128 * 32];
  __shared__ __align__(16) bf16 sB[128 * 32];
  const int tid = threadIdx.x;
  const int lane = tid & 63, wid = tid >> 6;
  const int wm = wid & 1, wn = wid >> 1;
  const int quad = lane >> 4, l16 = lane & 15;
  const int bm = blockIdx.y * 128, bn = blockIdx.x * 128;

  f32x4 acc[4][4] = {};

  const int srow = tid >> 2, scol = (tid & 3) << 3;
  const bf16* gA = A + (size_t)(bm + srow) * K + scol;
  const bf16* gB = Bw + (size_t)(bn + srow) * K + scol;
  const size_t row64 = (size_t)64 * K;

  for (int k0 = 0; k0 < K; k0 += 32) {
    glds16(gA + k0, &sA[tid * 8]);
    glds16(gA + k0 + row64, &sA[2048 + tid * 8]);
    glds16(gB + k0, &sB[tid * 8]);
    glds16(gB + k0 + row64, &sB[2048 + tid * 8]);
    __syncthreads();
    bf16x8 af[4], bff[4];
#pragma unroll
    for (int mt = 0; mt < 4; ++mt)
      af[mt] = *(const bf16x8*)&sA[(wm * 64 + mt * 16 + l16) * 32 + quad * 8];
#pragma unroll
    for (int nt = 0; nt < 4; ++nt)
      bff[nt] = *(const bf16x8*)&sB[(wn * 64 + nt * 16 + l16) * 32 + quad * 8];
#pragma unroll
    for (int mt = 0; mt < 4; ++mt)
#pragma unroll
      for (int nt = 0; nt < 4; ++nt)
        acc[mt][nt] = __builtin_amdgcn_mfma_f32_16x16x32_bf16(af[mt], bff[nt], acc[mt][nt], 0, 0, 0);
    __syncthreads();
  }

  if (MODE == 0) {
    bf16* C0 = (bf16*)C0v;
    const int which = blockIdx.x >> 4;
    const int h = blockIdx.x & 15;
#pragma unroll
    for (int mt = 0; mt < 4; ++mt) {
      const int m0 = bm + wm * 64 + mt * 16 + quad * 4;
      const int b = m0 >> 11, t0 = m0 & 2047;
#pragma unroll
      for (int nt = 0; nt < 4; ++nt) {
        const int hd = wn * 64 + nt * 16 + l16;
        if (which == 0) {
          bf16* dst = C0 + (((size_t)(b * 16 + h) * 2048 + t0) * 128 + hd);
#pragma unroll
          for (int r = 0; r < 4; ++r) dst[(size_t)r * 128] = (bf16)(acc[mt][nt][r] * QSCALE);
        } else if (which == 1) {
          bf16* dst = C1 + (((size_t)(b * 16 + h) * 2048 + t0) * 128 + hd);
#pragma unroll
          for (int r = 0; r < 4; ++r) dst[(size_t)r * 128] = (bf16)acc[mt][nt][r];
        } else {
          bh4 pk;
#pragma unroll
          for (int r = 0; r < 4; ++r) pk.v[r] = (bf16)acc[mt][nt][r];
          *(bh4*)(C2 + ((size_t)((b * 16 + h) * 128 + hd) * 2048 + t0)) = pk;
        }
      }
    }
  } else {
    float* C0 = (float*)C0v;  // fp32 final output
#pragma unroll
    for (int mt = 0; mt < 4; ++mt) {
      const int m0 = bm + wm * 64 + mt * 16 + quad * 4;
#pragma unroll
      for (int nt = 0; nt < 4; ++nt) {
        const int n = bn + wn * 64 + nt * 16 + l16;
#pragma unroll
        for (int r = 0; r < 4; ++r)
          C0[(size_t)(m0 + r) * N + n] = acc[mt][nt][r];
      }
    }
  }
}

// ---------------- Flash attention, transposed-S formulation ----------------
// S^T = K·Q^T (m=key, n=query); O^T = V^T·P^T. Q resident in registers.
// Round-1 polish additions:
//  * per-key-tile mask validity bitmap -> wave-uniform fast path (no per-elem
//    cndmask / mask loads in the hot loop; general-mask fallback kept)
//  * defer-max (T13, THR=8): skip O-rescale while tile max grows <= THR
//  * K tile prefetched into registers right after the tile-visible barrier and
//    ds_written at next iteration top -> HBM/L2 latency hidden under compute.
//    (+16 VGPR only; full K+V prefetch would cross the 170 reg/wave budget for
//    3 waves/SIMD.) V stays glds16.
__global__ __launch_bounds__(256, 3)
void attn_kernel(const bf16* __restrict__ Q, const bf16* __restrict__ Kb,
                 const bf16* __restrict__ Vt, const int* __restrict__ mask,
                 bf16* __restrict__ Y) {
  __shared__ __align__(16) bf16 smem[25600];  // 51200 B
  bf16* sK = smem;                 // 64 keys x 128 hd (swizzled chunks), 16 KB
  bf16* sV = smem + 8192;          // 128 hd x 64 keys (swizzled chunks), 16 KB
  bf16* sP = smem + 16384;         // per-wave 32 queries x 72 (pad), 18 KB

  const int tid = threadIdx.x;
  const int lane = tid & 63, w = tid >> 6;
  const int quad = lane >> 4, l16 = lane & 15;
  const int bh = blockIdx.x, b = bh >> 4, h = bh & 15;
  const int qt = blockIdx.y;
  const size_t head = (size_t)bh * (2048 * 128);

  // Q fragments resident: B-operand layout (lane = query, k = quad*8+j)
  bf16x8 qf[2][4];
#pragma unroll
  for (int nt = 0; nt < 2; ++nt) {
    const int t = qt * 128 + w * 32 + nt * 16 + l16;
    const bf16* g = Q + head + (size_t)t * 128 + quad * 8;
#pragma unroll
    for (int kk = 0; kk < 4; ++kk)
      qf[nt][kk] = *(const bf16x8*)(g + kk * 32);
  }

  f32x4 o[8][2] = {};                       // O^T: rows hd (8 tiles), cols query
  float mrow[2] = {-3.0e38f, -3.0e38f};
  float lrow[2] = {0.0f, 0.0f};

  const int* maskb = mask + b * 2048;
  bf16* sPw = sP + w * (32 * 72);

  // per-key-tile validity bitmap: lane l checks keys [l*32, l*32+32); tile kt
  // (64 keys) is fully valid iff bits 2kt and 2kt+1 are both set.
  unsigned long long vmask;
  {
    const int4* mp4 = (const int4*)maskb;
    bool ok = true;
#pragma unroll
    for (int j = 0; j < 8; ++j) {
      const int4 q4 = mp4[lane * 8 + j];
      ok = ok && (q4.x != 0) && (q4.y != 0) && (q4.z != 0) && (q4.w != 0);
    }
    vmask = __ballot(ok);
  }

  // staging geometry (identical addressing to the previous glds16 version)
  const int cpK = lane & 15, rbK = w * 16 + (lane >> 4);  // K: 16 chunks/row
  const int cpV = lane & 7,  rbV = w * 32 + (lane >> 3);  // V: 8 chunks/row

  int4 kreg[4];
  auto ldk = [&](int kt2) {
    const int key0 = kt2 * 64;
#pragma unroll
    for (int p = 0; p < 4; ++p) {
      const int row = rbK + p * 4;
      const int c = (cpK & 8) | ((cpK ^ row) & 7);
      kreg[p] = *(const int4*)(Kb + head + (size_t)(key0 + row) * 128 + c * 8);
    }
  };

  ldk(0);  // prefetch K tile 0

  for (int kt = 0; kt < 32; ++kt) {
    const int key0 = kt * 64;
    __syncthreads();  // A: all waves done reading previous tile's sK/sV

    // V stage for tile kt (DMA, issued first so it flies under the K writes)
#pragma unroll
    for (int p = 0; p < 4; ++p) {
      const int row = rbV + p * 8;
      const int c = cpV ^ (row & 7);
      glds16(Vt + head + (size_t)row * 2048 + key0 + c * 8,
             &sV[(w * 32 + p * 8) * 64 + lane * 8]);
    }
    // K tile kt: write the prefetched registers
#pragma unroll
    for (int p = 0; p < 4; ++p)
      *(int4*)&sK[(rbK + p * 4) * 128 + cpK * 8] = kreg[p];

    __syncthreads();  // B: tile visible (drains V DMA + K ds_writes)

    if (kt < 31) ldk(kt + 1);  // prefetch next K tile; lands during compute

    // S^T = K · Q^T : st[mt=key-tile][nt=query-tile]
    f32x4 st[4][2] = {};
#pragma unroll
    for (int kk = 0; kk < 4; ++kk) {
      bf16x8 ak[4];
#pragma unroll
      for (int mt = 0; mt < 4; ++mt) {
        const int row = mt * 16 + l16;
        const int c = kk * 4 + quad;
        const int cp = (c & 8) | ((c ^ row) & 7);
        ak[mt] = *(const bf16x8*)&sK[row * 128 + cp * 8];
      }
#pragma unroll
      for (int mt = 0; mt < 4; ++mt)
#pragma unroll
        for (int nt = 0; nt < 2; ++nt)
          st[mt][nt] = __builtin_amdgcn_mfma_f32_16x16x32_bf16(ak[mt], qf[nt][kk], st[mt][nt], 0, 0, 0);
    }

    const bool tileok = ((vmask >> (2 * kt)) & 3ULL) == 3ULL;

    if (tileok) {
      // fast path: no per-element mask ops; deferred-max rescale
#pragma unroll
      for (int nt = 0; nt < 2; ++nt) {
        float mx = -1.0e30f;
#pragma unroll
        for (int mt = 0; mt < 4; ++mt)
#pragma unroll
          for (int r = 0; r < 4; ++r) mx = fmaxf(mx, st[mt][nt][r]);
        mx = fmaxf(mx, __shfl_xor(mx, 16));
        mx = fmaxf(mx, __shfl_xor(mx, 32));
        if (!__all(mx <= mrow[nt] + DEFER_THR)) {
          const float newm = fmaxf(mrow[nt], mx);
          const float alpha = exp2f(mrow[nt] - newm);
          mrow[nt] = newm;
          lrow[nt] *= alpha;
#pragma unroll
          for (int mt = 0; mt < 8; ++mt)
#pragma unroll
            for (int r = 0; r < 4; ++r) o[mt][nt][r] *= alpha;
        }
        const float m = mrow[nt];
        float rs = 0.0f;
#pragma unroll
        for (int mt = 0; mt < 4; ++mt) {
          bh4 pk;
#pragma unroll
          for (int r = 0; r < 4; ++r) {
            const float p = exp2f(st[mt][nt][r] - m);
            rs += p;
            pk.v[r] = (bf16)p;
          }
          *(bh4*)&sPw[(nt * 16 + l16) * 72 + mt * 16 + quad * 4] = pk;
        }
        rs += __shfl_xor(rs, 16);
        rs += __shfl_xor(rs, 32);
        lrow[nt] += rs;
      }
    } else {
      // general-mask fallback (original path): key = 16*mt + 4*quad + r
      const int4* mp = (const int4*)(maskb + key0);
      int4 mm[4];
#pragma unroll
      for (int mt = 0; mt < 4; ++mt) mm[mt] = mp[mt * 4 + quad];
#pragma unroll
      for (int nt = 0; nt < 2; ++nt) {
        float mx = -1.0e30f;
#pragma unroll
        for (int mt = 0; mt < 4; ++mt) {
          const int* mi = (const int*)&mm[mt];
#pragma unroll
          for (int r = 0; r < 4; ++r) {
            float v = (mi[r] != 0) ? st[mt][nt][r] : -1.0e30f;
            st[mt][nt][r] = v;
            mx = fmaxf(mx, v);
          }
        }
        mx = fmaxf(mx, __shfl_xor(mx, 16));
        mx = fmaxf(mx, __shfl_xor(mx, 32));
        const float newm = fmaxf(mrow[nt], mx);
        const float alpha = exp2f(mrow[nt] - newm);
        mrow[nt] = newm;
        float rs = 0.0f;
#pragma unroll
        for (int mt = 0; mt < 4; ++mt) {
          const int* mi = (const int*)&mm[mt];
          bh4 pk;
#pragma unroll
          for (int r = 0; r < 4; ++r) {
            const float p = (mi[r] != 0) ? exp2f(st[mt][nt][r] - newm) : 0.0f;
            rs += p;
            pk.v[r] = (bf16)p;
          }
          *(bh4*)&sPw[(nt * 16 + l16) * 72 + mt * 16 + quad * 4] = pk;
        }
        rs += __shfl_xor(rs, 16);
        rs += __shfl_xor(rs, 32);
        lrow[nt] = lrow[nt] * alpha + rs;
#pragma unroll
        for (int mt = 0; mt < 8; ++mt)
#pragma unroll
          for (int r = 0; r < 4; ++r)
            o[mt][nt][r] *= alpha;
      }
    }

    // O^T += V^T · P^T  (wave-local sP: same-wave ds ordering suffices)
#pragma unroll
    for (int kk = 0; kk < 2; ++kk) {
      bf16x8 bp[2];
#pragma unroll
      for (int nt = 0; nt < 2; ++nt)
        bp[nt] = *(const bf16x8*)&sPw[(nt * 16 + l16) * 72 + kk * 32 + quad * 8];
#pragma unroll
      for (int mt = 0; mt < 8; ++mt) {
        const int row = mt * 16 + l16;
        const int c = kk * 4 + quad;
        bf16x8 av = *(const bf16x8*)&sV[row * 64 + (c ^ (row & 7)) * 8];
#pragma unroll
        for (int nt = 0; nt < 2; ++nt)
          o[mt][nt] = __builtin_amdgcn_mfma_f32_16x16x32_bf16(av, bp[nt], o[mt][nt], 0, 0, 0);
      }
    }
  }

  __syncthreads();  // last tile's sK/sV reads done before smem reuse below

  // epilogue: normalize, transpose O^T->O via per-wave LDS region, 16B stores
  bf16* sOw = smem + w * 4352;  // 32 rows x 136 stride (17408 elems total <= 25600)
#pragma unroll
  for (int nt = 0; nt < 2; ++nt) {
    const float inv = 1.0f / lrow[nt];
#pragma unroll
    for (int mt = 0; mt < 8; ++mt) {
      bh4 pk;
#pragma unroll
      for (int r = 0; r < 4; ++r) pk.v[r] = (bf16)(o[mt][nt][r] * inv);
      *(bh4*)&sOw[(nt * 16 + l16) * 136 + mt * 16 + quad * 4] = pk;
    }
  }
  // same-wave write->read: lgkmcnt ordering suffices, no barrier
  {
    const int col = (lane & 15) * 8;
#pragma unroll
    for (int p = 0; p < 8; ++p) {
      const int row = p * 4 + (lane >> 4);
      int4 v = *(const int4*)&sOw[row * 136 + col];
      const int token = qt * 128 + w * 32 + row;
      *(int4*)(Y + ((size_t)(b * 2048 + token)) * 2048 + h * 128 + col) = v;
    }
  }
}

extern "C" void kernel_launch(void* const* d_in, const int* in_sizes, int n_in,
                              void* d_out, int out_size, void* d_ws, size_t ws_size,
                              hipStream_t stream) {
  const float* x_raw  = (const float*)d_in[0];
  const int*   mask   = (const int*)d_in[1];
  const float* wq_raw = (const float*)d_in[2];
  const float* wo_raw = (const float*)d_in[3];
  float* out = (float*)d_out;  // reference output dtype is fp32

  char* ws = (char*)d_ws;
  const size_t MB = 1024 * 1024;
  bf16* xb  = (bf16*)(ws + 256);              // 32 MiB  (x bf16; later reused as yb)
  bf16* wqb = (bf16*)(ws + 256 + 32 * MB);    // 24 MiB  (w_qkv bf16; later reused as wob)
  bf16* qb  = (bf16*)(ws + 256 + 56 * MB);    // 32 MiB  (B,H,T,HD) pre-scaled
  bf16* kb  = (bf16*)(ws + 256 + 88 * MB);    // 32 MiB  (B,H,T,HD)
  bf16* vt  = (bf16*)(ws + 256 + 120 * MB);   // 32 MiB  (B,H,HD,T)
  bf16* yb  = xb;                             // attention output (B,T,D)
  bf16* wob = wqb;                            // w_o bf16 (converted after gemm1)

  convert_to_bf16<<<1024, 256, 0, stream>>>(x_raw, xb, (long)in_sizes[0]);
  convert_to_bf16<<<1024, 256, 0, stream>>>(wq_raw, wqb, (long)in_sizes[2]);

  // qkv projection (M=8192, N=6144, K=2048), scatter to per-head layouts
  gemm_bt<0><<<dim3(48, 64), 256, 0, stream>>>(xb, wqb, qb, kb, vt, 8192, 6144, 2048);

  // w_o conversion (overwrites wqb region — dead after gemm1)
  convert_to_bf16<<<1024, 256, 0, stream>>>(wo_raw, wob, (long)in_sizes[3]);

  // fused flash attention (writes yb = xb region — x dead after gemm1)
  attn_kernel<<<dim3(64, 16), 256, 0, stream>>>(qb, kb, vt, mask, yb);

  // output projection (M=8192, N=2048, K=2048), fp32 out
  gemm_bt<1><<<dim3(16, 64), 256, 0, stream>>>(yb, wob, out, nullptr, nullptr, 8192, 2048, 2048);
}

// Round 2
// 945.032 us; speedup vs baseline: 1.2543x; 1.2543x over previous
//
#include <hip/hip_runtime.h>
#include <hip/hip_bf16.h>

typedef __bf16 bf16;
typedef bf16 bf16x8 __attribute__((ext_vector_type(8)));
typedef float f32x4 __attribute__((ext_vector_type(4)));

struct alignas(8) bh4 { bf16 v[4]; };

// async global->LDS, 16B per lane. LDS dest must be wave-uniform base + lane*16.
__device__ __forceinline__ void glds16(const bf16* g, bf16* l) {
  __builtin_amdgcn_global_load_lds(
      (const __attribute__((address_space(1))) void*)g,
      (__attribute__((address_space(3))) void*)l, 16, 0, 0);
}

// log2(e) / sqrt(128): folded into Q so softmax uses exp2 (native v_exp_f32)
#define QSCALE (1.4426950408889634f / 11.313708498984761f)
// defer-max threshold (log2 domain): skip O-rescale while tile max grows <= 8.
// P values then bounded by 2^8=256 — safe in bf16/f32 accum (HK THR=8 regime).
#define DEFER_THR 8.0f

// fp32 -> bf16 conversion (inputs are fp32; established round 2).
__global__ void convert_to_bf16(const float* __restrict__ s, bf16* __restrict__ dst,
                                long n) {
  const long stride = (long)gridDim.x * blockDim.x * 8;
  for (long i = ((long)blockIdx.x * blockDim.x + threadIdx.x) * 8; i < n; i += stride) {
    float4 a = *(const float4*)(s + i);
    float4 b = *(const float4*)(s + i + 4);
    bf16x8 o;
    o[0] = (bf16)a.x; o[1] = (bf16)a.y; o[2] = (bf16)a.z; o[3] = (bf16)a.w;
    o[4] = (bf16)b.x; o[5] = (bf16)b.y; o[6] = (bf16)b.z; o[7] = (bf16)b.w;
    *(bf16x8*)(dst + i) = o;
  }
}

// ---------------- GEMM: C = A (M,K) * Bw^T, Bw is (N,K) row-major ----------
// 128x128 tile, BK=32, 4 waves 2x2 (verified round 3).
template <int MODE>
__global__ void gemm_bt(const bf16* __restrict__ A, const bf16* __restrict__ Bw,
                        void* __restrict__ C0v, bf16* __restrict__ C1,
                        bf16* __restrict__ C2, int M, int N, int K) {
  __shared__ __align__(16) bf16 sA[128 * 32];
  __shared__ __align__(16) bf16 sB[128 * 32];
  const int tid = threadIdx.x;
  const int lane = tid & 63, wid = tid >> 6;
  const int wm = wid & 1, wn = wid >> 1;
  const int quad = lane >> 4, l16 = lane & 15;
  const int bm = blockIdx.y * 128, bn = blockIdx.x * 128;

  f32x4 acc[4][4] = {};

  const int srow = tid >> 2, scol = (tid & 3) << 3;
  const bf16* gA = A + (size_t)(bm + srow) * K + scol;
  const bf16* gB = Bw + (size_t)(bn + srow) * K + scol;
  const size_t row64 = (size_t)64 * K;

  for (int k0 = 0; k0 < K; k0 += 32) {
    glds16(gA + k0, &sA[tid * 8]);
    glds16(gA + k0 + row64, &sA[2048 + tid * 8]);
    glds16(gB + k0, &sB[tid * 8]);
    glds16(gB + k0 + row64, &sB[2048 + tid * 8]);
    __syncthreads();
    bf16x8 af[4], bff[4];
#pragma unroll
    for (int mt = 0; mt < 4; ++mt)
      af[mt] = *(const bf16x8*)&sA[(wm * 64 + mt * 16 + l16) * 32 + quad * 8];
#pragma unroll
    for (int nt = 0; nt < 4; ++nt)
      bff[nt] = *(const bf16x8*)&sB[(wn * 64 + nt * 16 + l16) * 32 + quad * 8];
#pragma unroll
    for (int mt = 0; mt < 4; ++mt)
#pragma unroll
      for (int nt = 0; nt < 4; ++nt)
        acc[mt][nt] = __builtin_amdgcn_mfma_f32_16x16x32_bf16(af[mt], bff[nt], acc[mt][nt], 0, 0, 0);
    __syncthreads();
  }

  if (MODE == 0) {
    bf16* C0 = (bf16*)C0v;
    const int which = blockIdx.x >> 4;
    const int h = blockIdx.x & 15;
#pragma unroll
    for (int mt = 0; mt < 4; ++mt) {
      const int m0 = bm + wm * 64 + mt * 16 + quad * 4;
      const int b = m0 >> 11, t0 = m0 & 2047;
#pragma unroll
      for (int nt = 0; nt < 4; ++nt) {
        const int hd = wn * 64 + nt * 16 + l16;
        if (which == 0) {
          bf16* dst = C0 + (((size_t)(b * 16 + h) * 2048 + t0) * 128 + hd);
#pragma unroll
          for (int r = 0; r < 4; ++r) dst[(size_t)r * 128] = (bf16)(acc[mt][nt][r] * QSCALE);
        } else if (which == 1) {
          bf16* dst = C1 + (((size_t)(b * 16 + h) * 2048 + t0) * 128 + hd);
#pragma unroll
          for (int r = 0; r < 4; ++r) dst[(size_t)r * 128] = (bf16)acc[mt][nt][r];
        } else {
          bh4 pk;
#pragma unroll
          for (int r = 0; r < 4; ++r) pk.v[r] = (bf16)acc[mt][nt][r];
          *(bh4*)(C2 + ((size_t)((b * 16 + h) * 128 + hd) * 2048 + t0)) = pk;
        }
      }
    }
  } else {
    float* C0 = (float*)C0v;  // fp32 final output
#pragma unroll
    for (int mt = 0; mt < 4; ++mt) {
      const int m0 = bm + wm * 64 + mt * 16 + quad * 4;
#pragma unroll
      for (int nt = 0; nt < 4; ++nt) {
        const int n = bn + wn * 64 + nt * 16 + l16;
#pragma unroll
        for (int r = 0; r < 4; ++r)
          C0[(size_t)(m0 + r) * N + n] = acc[mt][nt][r];
      }
    }
  }
}

// ---------------- Flash attention, transposed-S formulation ----------------
// S^T = K·Q^T (m=key, n=query); O^T = V^T·P^T. Q resident in registers.
// K/V staged via glds16 with XOR chunk swizzle (round-0 structure: 296 us,
// zero scratch). Round-2 additions (no added register lifetime):
//  * per-key-tile mask validity bitmap -> wave-uniform fast path (no per-elem
//    cndmask / mask loads in the hot loop; general-mask fallback kept)
//  * defer-max (T13, THR=8): skip O-rescale while tile max grows <= THR
// NOTE round-1 lesson: K-tile register prefetch (kreg[4] live across the whole
// compute phase) spilled to scratch (WRITE_SIZE 52MB -> 1.16GB, 2.5x slower).
// Do not reintroduce loop-spanning register prefetch under (256,3) bounds.
__global__ __launch_bounds__(256, 3)
void attn_kernel(const bf16* __restrict__ Q, const bf16* __restrict__ Kb,
                 const bf16* __restrict__ Vt, const int* __restrict__ mask,
                 bf16* __restrict__ Y) {
  __shared__ __align__(16) bf16 smem[25600];  // 51200 B
  bf16* sK = smem;                 // 64 keys x 128 hd (swizzled chunks), 16 KB
  bf16* sV = smem + 8192;          // 128 hd x 64 keys (swizzled chunks), 16 KB
  bf16* sP = smem + 16384;         // per-wave 32 queries x 72 (pad), 18 KB

  const int tid = threadIdx.x;
  const int lane = tid & 63, w = tid >> 6;
  const int quad = lane >> 4, l16 = lane & 15;
  const int bh = blockIdx.x, b = bh >> 4, h = bh & 15;
  const int qt = blockIdx.y;
  const size_t head = (size_t)bh * (2048 * 128);

  // Q fragments resident: B-operand layout (lane = query, k = quad*8+j)
  bf16x8 qf[2][4];
#pragma unroll
  for (int nt = 0; nt < 2; ++nt) {
    const int t = qt * 128 + w * 32 + nt * 16 + l16;
    const bf16* g = Q + head + (size_t)t * 128 + quad * 8;
#pragma unroll
    for (int kk = 0; kk < 4; ++kk)
      qf[nt][kk] = *(const bf16x8*)(g + kk * 32);
  }

  f32x4 o[8][2] = {};                       // O^T: rows hd (8 tiles), cols query
  float mrow[2] = {-3.0e38f, -3.0e38f};
  float lrow[2] = {0.0f, 0.0f};

  const int* maskb = mask + b * 2048;
  bf16* sPw = sP + w * (32 * 72);

  // per-key-tile validity bitmap: lane l checks keys [l*32, l*32+32); tile kt
  // (64 keys) is fully valid iff bits 2kt and 2kt+1 are both set.
  unsigned long long vmask;
  {
    const int4* mp4 = (const int4*)maskb;
    bool ok = true;
#pragma unroll
    for (int j = 0; j < 8; ++j) {
      const int4 q4 = mp4[lane * 8 + j];
      ok = ok && (q4.x != 0) && (q4.y != 0) && (q4.z != 0) && (q4.w != 0);
    }
    vmask = __ballot(ok);
  }

  for (int kt = 0; kt < 32; ++kt) {
    const int key0 = kt * 64;
    {  // stage K tile (64 keys x 128 hd = 16 chunks/row), swizzled
      const int cp = lane & 15;
      const int rbase = w * 16 + (lane >> 4);
#pragma unroll
      for (int p = 0; p < 4; ++p) {
        const int row = rbase + p * 4;
        const int c = (cp & 8) | ((cp ^ row) & 7);
        glds16(Kb + head + (size_t)(key0 + row) * 128 + c * 8,
               &sK[(w * 16 + p * 4) * 128 + lane * 8]);
      }
    }
    {  // stage V^T tile (128 hd x 64 keys = 8 chunks/row), swizzled
      const int cp = lane & 7;
      const int rbase = w * 32 + (lane >> 3);
#pragma unroll
      for (int p = 0; p < 4; ++p) {
        const int row = rbase + p * 8;
        const int c = cp ^ (row & 7);
        glds16(Vt + head + (size_t)row * 2048 + key0 + c * 8,
               &sV[(w * 32 + p * 8) * 64 + lane * 8]);
      }
    }
    __syncthreads();

    // S^T = K · Q^T : st[mt=key-tile][nt=query-tile]
    f32x4 st[4][2] = {};
#pragma unroll
    for (int kk = 0; kk < 4; ++kk) {
      bf16x8 ak[4];
#pragma unroll
      for (int mt = 0; mt < 4; ++mt) {
        const int row = mt * 16 + l16;
        const int c = kk * 4 + quad;
        const int cp = (c & 8) | ((c ^ row) & 7);
        ak[mt] = *(const bf16x8*)&sK[row * 128 + cp * 8];
      }
#pragma unroll
      for (int mt = 0; mt < 4; ++mt)
#pragma unroll
        for (int nt = 0; nt < 2; ++nt)
          st[mt][nt] = __builtin_amdgcn_mfma_f32_16x16x32_bf16(ak[mt], qf[nt][kk], st[mt][nt], 0, 0, 0);
    }

    const bool tileok = ((vmask >> (2 * kt)) & 3ULL) == 3ULL;

    if (tileok) {
      // fast path: no per-element mask ops; deferred-max rescale (T13)
#pragma unroll
      for (int nt = 0; nt < 2; ++nt) {
        float mx = -1.0e30f;
#pragma unroll
        for (int mt = 0; mt < 4; ++mt)
#pragma unroll
          for (int r = 0; r < 4; ++r) mx = fmaxf(mx, st[mt][nt][r]);
        mx = fmaxf(mx, __shfl_xor(mx, 16));
        mx = fmaxf(mx, __shfl_xor(mx, 32));
        if (!__all(mx <= mrow[nt] + DEFER_THR)) {
          const float newm = fmaxf(mrow[nt], mx);
          const float alpha = exp2f(mrow[nt] - newm);
          mrow[nt] = newm;
          lrow[nt] *= alpha;
#pragma unroll
          for (int mt = 0; mt < 8; ++mt)
#pragma unroll
            for (int r = 0; r < 4; ++r) o[mt][nt][r] *= alpha;
        }
        const float m = mrow[nt];
        float rs = 0.0f;
#pragma unroll
        for (int mt = 0; mt < 4; ++mt) {
          bh4 pk;
#pragma unroll
          for (int r = 0; r < 4; ++r) {
            const float p = exp2f(st[mt][nt][r] - m);
            rs += p;
            pk.v[r] = (bf16)p;
          }
          *(bh4*)&sPw[(nt * 16 + l16) * 72 + mt * 16 + quad * 4] = pk;
        }
        rs += __shfl_xor(rs, 16);
        rs += __shfl_xor(rs, 32);
        lrow[nt] += rs;
      }
    } else {
      // general-mask fallback (original path): key = 16*mt + 4*quad + r
      const int4* mp = (const int4*)(maskb + key0);
      int4 mm[4];
#pragma unroll
      for (int mt = 0; mt < 4; ++mt) mm[mt] = mp[mt * 4 + quad];
#pragma unroll
      for (int nt = 0; nt < 2; ++nt) {
        float mx = -1.0e30f;
#pragma unroll
        for (int mt = 0; mt < 4; ++mt) {
          const int* mi = (const int*)&mm[mt];
#pragma unroll
          for (int r = 0; r < 4; ++r) {
            float v = (mi[r] != 0) ? st[mt][nt][r] : -1.0e30f;
            st[mt][nt][r] = v;
            mx = fmaxf(mx, v);
          }
        }
        mx = fmaxf(mx, __shfl_xor(mx, 16));
        mx = fmaxf(mx, __shfl_xor(mx, 32));
        const float newm = fmaxf(mrow[nt], mx);
        const float alpha = exp2f(mrow[nt] - newm);
        mrow[nt] = newm;
        float rs = 0.0f;
#pragma unroll
        for (int mt = 0; mt < 4; ++mt) {
          const int* mi = (const int*)&mm[mt];
          bh4 pk;
#pragma unroll
          for (int r = 0; r < 4; ++r) {
            const float p = (mi[r] != 0) ? exp2f(st[mt][nt][r] - newm) : 0.0f;
            rs += p;
            pk.v[r] = (bf16)p;
          }
          *(bh4*)&sPw[(nt * 16 + l16) * 72 + mt * 16 + quad * 4] = pk;
        }
        rs += __shfl_xor(rs, 16);
        rs += __shfl_xor(rs, 32);
        lrow[nt] = lrow[nt] * alpha + rs;
#pragma unroll
        for (int mt = 0; mt < 8; ++mt)
#pragma unroll
          for (int r = 0; r < 4; ++r)
            o[mt][nt][r] *= alpha;
      }
    }

    // O^T += V^T · P^T  (wave-local sP: same-wave ds ordering suffices)
#pragma unroll
    for (int kk = 0; kk < 2; ++kk) {
      bf16x8 bp[2];
#pragma unroll
      for (int nt = 0; nt < 2; ++nt)
        bp[nt] = *(const bf16x8*)&sPw[(nt * 16 + l16) * 72 + kk * 32 + quad * 8];
#pragma unroll
      for (int mt = 0; mt < 8; ++mt) {
        const int row = mt * 16 + l16;
        const int c = kk * 4 + quad;
        bf16x8 av = *(const bf16x8*)&sV[row * 64 + (c ^ (row & 7)) * 8];
#pragma unroll
        for (int nt = 0; nt < 2; ++nt)
          o[mt][nt] = __builtin_amdgcn_mfma_f32_16x16x32_bf16(av, bp[nt], o[mt][nt], 0, 0, 0);
      }
    }
    __syncthreads();  // sK/sV reads done before next staging
  }

  // epilogue: normalize, transpose O^T->O via per-wave LDS region, 16B stores
  bf16* sOw = smem + w * 4352;  // 32 rows x 136 stride (17408 elems total <= 25600)
#pragma unroll
  for (int nt = 0; nt < 2; ++nt) {
    const float inv = 1.0f / lrow[nt];
#pragma unroll
    for (int mt = 0; mt < 8; ++mt) {
      bh4 pk;
#pragma unroll
      for (int r = 0; r < 4; ++r) pk.v[r] = (bf16)(o[mt][nt][r] * inv);
      *(bh4*)&sOw[(nt * 16 + l16) * 136 + mt * 16 + quad * 4] = pk;
    }
  }
  // same-wave write->read: lgkmcnt ordering suffices, no barrier
  {
    const int col = (lane & 15) * 8;
#pragma unroll
    for (int p = 0; p < 8; ++p) {
      const int row = p * 4 + (lane >> 4);
      int4 v = *(const int4*)&sOw[row * 136 + col];
      const int token = qt * 128 + w * 32 + row;
      *(int4*)(Y + ((size_t)(b * 2048 + token)) * 2048 + h * 128 + col) = v;
    }
  }
}

extern "C" void kernel_launch(void* const* d_in, const int* in_sizes, int n_in,
                              void* d_out, int out_size, void* d_ws, size_t ws_size,
                              hipStream_t stream) {
  const float* x_raw  = (const float*)d_in[0];
  const int*   mask   = (const int*)d_in[1];
  const float* wq_raw = (const float*)d_in[2];
  const float* wo_raw = (const float*)d_in[3];
  float* out = (float*)d_out;  // reference output dtype is fp32

  char* ws = (char*)d_ws;
  const size_t MB = 1024 * 1024;
  bf16* xb  = (bf16*)(ws + 256);              // 32 MiB  (x bf16; later reused as yb)
  bf16* wqb = (bf16*)(ws + 256 + 32 * MB);    // 24 MiB  (w_qkv bf16; later reused as wob)
  bf16* qb  = (bf16*)(ws + 256 + 56 * MB);    // 32 MiB  (B,H,T,HD) pre-scaled
  bf16* kb  = (bf16*)(ws + 256 + 88 * MB);    // 32 MiB  (B,H,T,HD)
  bf16* vt  = (bf16*)(ws + 256 + 120 * MB);   // 32 MiB  (B,H,HD,T)
  bf16* yb  = xb;                             // attention output (B,T,D)
  bf16* wob = wqb;                            // w_o bf16 (converted after gemm1)

  convert_to_bf16<<<1024, 256, 0, stream>>>(x_raw, xb, (long)in_sizes[0]);
  convert_to_bf16<<<1024, 256, 0, stream>>>(wq_raw, wqb, (long)in_sizes[2]);

  // qkv projection (M=8192, N=6144, K=2048), scatter to per-head layouts
  gemm_bt<0><<<dim3(48, 64), 256, 0, stream>>>(xb, wqb, qb, kb, vt, 8192, 6144, 2048);

  // w_o conversion (overwrites wqb region — dead after gemm1)
  convert_to_bf16<<<1024, 256, 0, stream>>>(wo_raw, wob, (long)in_sizes[3]);

  // fused flash attention (writes yb = xb region — x dead after gemm1)
  attn_kernel<<<dim3(64, 16), 256, 0, stream>>>(qb, kb, vt, mask, yb);

  // output projection (M=8192, N=2048, K=2048), fp32 out
  gemm_bt<1><<<dim3(16, 64), 256, 0, stream>>>(yb, wob, out, nullptr, nullptr, 8192, 2048, 2048);
}

// Round 3
// 670.654 us; speedup vs baseline: 1.7675x; 1.4091x over previous
//
#include <hip/hip_runtime.h>
#include <hip/hip_bf16.h>

typedef __bf16 bf16;
typedef bf16 bf16x8 __attribute__((ext_vector_type(8)));
typedef float f32x4 __attribute__((ext_vector_type(4)));

struct alignas(8) bh4 { bf16 v[4]; };

// async global->LDS, 16B per lane. LDS dest must be wave-uniform base + lane*16.
__device__ __forceinline__ void glds16(const bf16* g, bf16* l) {
  __builtin_amdgcn_global_load_lds(
      (const __attribute__((address_space(1))) void*)g,
      (__attribute__((address_space(3))) void*)l, 16, 0, 0);
}

// log2(e) / sqrt(128): folded into Q so softmax uses exp2 (native v_exp_f32)
#define QSCALE (1.4426950408889634f / 11.313708498984761f)
// defer-max threshold (log2 domain): skip O-rescale while tile max grows <= 8.
// P values then bounded by 2^8=256 — safe in bf16/f32 accum (HK THR=8 regime).
#define DEFER_THR 8.0f

// fp32 -> bf16 conversion (inputs are fp32; established round 2).
__global__ void convert_to_bf16(const float* __restrict__ s, bf16* __restrict__ dst,
                                long n) {
  const long stride = (long)gridDim.x * blockDim.x * 8;
  for (long i = ((long)blockIdx.x * blockDim.x + threadIdx.x) * 8; i < n; i += stride) {
    float4 a = *(const float4*)(s + i);
    float4 b = *(const float4*)(s + i + 4);
    bf16x8 o;
    o[0] = (bf16)a.x; o[1] = (bf16)a.y; o[2] = (bf16)a.z; o[3] = (bf16)a.w;
    o[4] = (bf16)b.x; o[5] = (bf16)b.y; o[6] = (bf16)b.z; o[7] = (bf16)b.w;
    *(bf16x8*)(dst + i) = o;
  }
}

// ---------------- GEMM: C = A (M,K) * Bw^T, Bw is (N,K) row-major ----------
// 128x128 tile, BK=32, 4 waves 2x2 (verified round 3).
template <int MODE>
__global__ void gemm_bt(const bf16* __restrict__ A, const bf16* __restrict__ Bw,
                        void* __restrict__ C0v, bf16* __restrict__ C1,
                        bf16* __restrict__ C2, int M, int N, int K) {
  __shared__ __align__(16) bf16 sA[128 * 32];
  __shared__ __align__(16) bf16 sB[128 * 32];
  const int tid = threadIdx.x;
  const int lane = tid & 63, wid = tid >> 6;
  const int wm = wid & 1, wn = wid >> 1;
  const int quad = lane >> 4, l16 = lane & 15;
  const int bm = blockIdx.y * 128, bn = blockIdx.x * 128;

  f32x4 acc[4][4] = {};

  const int srow = tid >> 2, scol = (tid & 3) << 3;
  const bf16* gA = A + (size_t)(bm + srow) * K + scol;
  const bf16* gB = Bw + (size_t)(bn + srow) * K + scol;
  const size_t row64 = (size_t)64 * K;

  for (int k0 = 0; k0 < K; k0 += 32) {
    glds16(gA + k0, &sA[tid * 8]);
    glds16(gA + k0 + row64, &sA[2048 + tid * 8]);
    glds16(gB + k0, &sB[tid * 8]);
    glds16(gB + k0 + row64, &sB[2048 + tid * 8]);
    __syncthreads();
    bf16x8 af[4], bff[4];
#pragma unroll
    for (int mt = 0; mt < 4; ++mt)
      af[mt] = *(const bf16x8*)&sA[(wm * 64 + mt * 16 + l16) * 32 + quad * 8];
#pragma unroll
    for (int nt = 0; nt < 4; ++nt)
      bff[nt] = *(const bf16x8*)&sB[(wn * 64 + nt * 16 + l16) * 32 + quad * 8];
#pragma unroll
    for (int mt = 0; mt < 4; ++mt)
#pragma unroll
      for (int nt = 0; nt < 4; ++nt)
        acc[mt][nt] = __builtin_amdgcn_mfma_f32_16x16x32_bf16(af[mt], bff[nt], acc[mt][nt], 0, 0, 0);
    __syncthreads();
  }

  if (MODE == 0) {
    bf16* C0 = (bf16*)C0v;
    const int which = blockIdx.x >> 4;
    const int h = blockIdx.x & 15;
#pragma unroll
    for (int mt = 0; mt < 4; ++mt) {
      const int m0 = bm + wm * 64 + mt * 16 + quad * 4;
      const int b = m0 >> 11, t0 = m0 & 2047;
#pragma unroll
      for (int nt = 0; nt < 4; ++nt) {
        const int hd = wn * 64 + nt * 16 + l16;
        if (which == 0) {
          bf16* dst = C0 + (((size_t)(b * 16 + h) * 2048 + t0) * 128 + hd);
#pragma unroll
          for (int r = 0; r < 4; ++r) dst[(size_t)r * 128] = (bf16)(acc[mt][nt][r] * QSCALE);
        } else if (which == 1) {
          bf16* dst = C1 + (((size_t)(b * 16 + h) * 2048 + t0) * 128 + hd);
#pragma unroll
          for (int r = 0; r < 4; ++r) dst[(size_t)r * 128] = (bf16)acc[mt][nt][r];
        } else {
          bh4 pk;
#pragma unroll
          for (int r = 0; r < 4; ++r) pk.v[r] = (bf16)acc[mt][nt][r];
          *(bh4*)(C2 + ((size_t)((b * 16 + h) * 128 + hd) * 2048 + t0)) = pk;
        }
      }
    }
  } else {
    float* C0 = (float*)C0v;  // fp32 final output
#pragma unroll
    for (int mt = 0; mt < 4; ++mt) {
      const int m0 = bm + wm * 64 + mt * 16 + quad * 4;
#pragma unroll
      for (int nt = 0; nt < 4; ++nt) {
        const int n = bn + wn * 64 + nt * 16 + l16;
#pragma unroll
        for (int r = 0; r < 4; ++r)
          C0[(size_t)(m0 + r) * N + n] = acc[mt][nt][r];
      }
    }
  }
}

// ---------------- Flash attention, transposed-S formulation ----------------
// S^T = K·Q^T (m=key, n=query); O^T = V^T·P^T. Q resident in registers.
// K/V staged via glds16 with XOR chunk swizzle (round-0 structure: 296 us,
// zero scratch).
// Round-3: SINGLE softmax path. Mask handling is a tiny wave-uniform cold
// block (scalar mask loads, st := -1e30 in place) feeding the common
// defer-max softmax; masked entries become exp2(-1e30 - m) = 0.
// Lessons (do not regress):
//  * r1: loop-spanning register prefetch (kreg[4]) -> scratch spill, 2.5x.
//  * r2: duplicated fast/fallback softmax bodies -> regalloc worst-case over
//    both paths (st32+o64+qf16+mm16) > 168-reg cap at 3 waves/SIMD -> spill
//    (WRITE 52MB->640MB). Keep ONE softmax body; cold path touches <=2 regs.
__global__ __launch_bounds__(256, 3)
void attn_kernel(const bf16* __restrict__ Q, const bf16* __restrict__ Kb,
                 const bf16* __restrict__ Vt, const int* __restrict__ mask,
                 bf16* __restrict__ Y) {
  __shared__ __align__(16) bf16 smem[25600];  // 51200 B
  bf16* sK = smem;                 // 64 keys x 128 hd (swizzled chunks), 16 KB
  bf16* sV = smem + 8192;          // 128 hd x 64 keys (swizzled chunks), 16 KB
  bf16* sP = smem + 16384;         // per-wave 32 queries x 72 (pad), 18 KB

  const int tid = threadIdx.x;
  const int lane = tid & 63, w = tid >> 6;
  const int quad = lane >> 4, l16 = lane & 15;
  const int bh = blockIdx.x, b = bh >> 4, h = bh & 15;
  const int qt = blockIdx.y;
  const size_t head = (size_t)bh * (2048 * 128);

  // Q fragments resident: B-operand layout (lane = query, k = quad*8+j)
  bf16x8 qf[2][4];
#pragma unroll
  for (int nt = 0; nt < 2; ++nt) {
    const int t = qt * 128 + w * 32 + nt * 16 + l16;
    const bf16* g = Q + head + (size_t)t * 128 + quad * 8;
#pragma unroll
    for (int kk = 0; kk < 4; ++kk)
      qf[nt][kk] = *(const bf16x8*)(g + kk * 32);
  }

  f32x4 o[8][2] = {};                       // O^T: rows hd (8 tiles), cols query
  float mrow[2] = {-3.0e38f, -3.0e38f};
  float lrow[2] = {0.0f, 0.0f};

  const int* maskb = mask + b * 2048;
  bf16* sPw = sP + w * (32 * 72);

  // per-key-tile validity bitmap: lane l checks keys [l*32, l*32+32); tile kt
  // (64 keys) is fully valid iff bits 2kt and 2kt+1 are both set.
  unsigned long long vmask;
  {
    const int4* mp4 = (const int4*)maskb;
    bool ok = true;
#pragma unroll
    for (int j = 0; j < 8; ++j) {
      const int4 q4 = mp4[lane * 8 + j];
      ok = ok && (q4.x != 0) && (q4.y != 0) && (q4.z != 0) && (q4.w != 0);
    }
    vmask = __ballot(ok);
  }

  for (int kt = 0; kt < 32; ++kt) {
    const int key0 = kt * 64;
    {  // stage K tile (64 keys x 128 hd = 16 chunks/row), swizzled
      const int cp = lane & 15;
      const int rbase = w * 16 + (lane >> 4);
#pragma unroll
      for (int p = 0; p < 4; ++p) {
        const int row = rbase + p * 4;
        const int c = (cp & 8) | ((cp ^ row) & 7);
        glds16(Kb + head + (size_t)(key0 + row) * 128 + c * 8,
               &sK[(w * 16 + p * 4) * 128 + lane * 8]);
      }
    }
    {  // stage V^T tile (128 hd x 64 keys = 8 chunks/row), swizzled
      const int cp = lane & 7;
      const int rbase = w * 32 + (lane >> 3);
#pragma unroll
      for (int p = 0; p < 4; ++p) {
        const int row = rbase + p * 8;
        const int c = cp ^ (row & 7);
        glds16(Vt + head + (size_t)row * 2048 + key0 + c * 8,
               &sV[(w * 32 + p * 8) * 64 + lane * 8]);
      }
    }
    __syncthreads();

    // S^T = K · Q^T : st[mt=key-tile][nt=query-tile]
    f32x4 st[4][2] = {};
#pragma unroll
    for (int kk = 0; kk < 4; ++kk) {
      bf16x8 ak[4];
#pragma unroll
      for (int mt = 0; mt < 4; ++mt) {
        const int row = mt * 16 + l16;
        const int c = kk * 4 + quad;
        const int cp = (c & 8) | ((c ^ row) & 7);
        ak[mt] = *(const bf16x8*)&sK[row * 128 + cp * 8];
      }
#pragma unroll
      for (int mt = 0; mt < 4; ++mt)
#pragma unroll
        for (int nt = 0; nt < 2; ++nt)
          st[mt][nt] = __builtin_amdgcn_mfma_f32_16x16x32_bf16(ak[mt], qf[nt][kk], st[mt][nt], 0, 0, 0);
    }

    // cold path: partially-masked tile -> neutralize masked keys in place.
    // key = 16*mt + 4*quad + r; scalar loads, ~2 transient regs.
    if (((vmask >> (2 * kt)) & 3ULL) != 3ULL) {
#pragma unroll
      for (int mt = 0; mt < 4; ++mt) {
#pragma unroll
        for (int r = 0; r < 4; ++r) {
          const int mk = maskb[key0 + mt * 16 + quad * 4 + r];
#pragma unroll
          for (int nt = 0; nt < 2; ++nt)
            if (mk == 0) { st[mt][nt][r] = -1.0e30f; }
        }
      }
    }

    // single softmax path, defer-max (T13)
#pragma unroll
    for (int nt = 0; nt < 2; ++nt) {
      float mx = -1.0e30f;
#pragma unroll
      for (int mt = 0; mt < 4; ++mt)
#pragma unroll
        for (int r = 0; r < 4; ++r) mx = fmaxf(mx, st[mt][nt][r]);
      mx = fmaxf(mx, __shfl_xor(mx, 16));
      mx = fmaxf(mx, __shfl_xor(mx, 32));
      if (!__all(mx <= mrow[nt] + DEFER_THR)) {
        const float newm = fmaxf(mrow[nt], mx);
        const float alpha = exp2f(mrow[nt] - newm);
        mrow[nt] = newm;
        lrow[nt] *= alpha;
#pragma unroll
        for (int mt = 0; mt < 8; ++mt)
#pragma unroll
          for (int r = 0; r < 4; ++r) o[mt][nt][r] *= alpha;
      }
      const float m = mrow[nt];
      float rs = 0.0f;
#pragma unroll
      for (int mt = 0; mt < 4; ++mt) {
        bh4 pk;
#pragma unroll
        for (int r = 0; r < 4; ++r) {
          const float p = exp2f(st[mt][nt][r] - m);
          rs += p;
          pk.v[r] = (bf16)p;
        }
        *(bh4*)&sPw[(nt * 16 + l16) * 72 + mt * 16 + quad * 4] = pk;
      }
      rs += __shfl_xor(rs, 16);
      rs += __shfl_xor(rs, 32);
      lrow[nt] += rs;
    }

    // O^T += V^T · P^T  (wave-local sP: same-wave ds ordering suffices)
#pragma unroll
    for (int kk = 0; kk < 2; ++kk) {
      bf16x8 bp[2];
#pragma unroll
      for (int nt = 0; nt < 2; ++nt)
        bp[nt] = *(const bf16x8*)&sPw[(nt * 16 + l16) * 72 + kk * 32 + quad * 8];
#pragma unroll
      for (int mt = 0; mt < 8; ++mt) {
        const int row = mt * 16 + l16;
        const int c = kk * 4 + quad;
        bf16x8 av = *(const bf16x8*)&sV[row * 64 + (c ^ (row & 7)) * 8];
#pragma unroll
        for (int nt = 0; nt < 2; ++nt)
          o[mt][nt] = __builtin_amdgcn_mfma_f32_16x16x32_bf16(av, bp[nt], o[mt][nt], 0, 0, 0);
      }
    }
    __syncthreads();  // sK/sV reads done before next staging
  }

  // epilogue: normalize, transpose O^T->O via per-wave LDS region, 16B stores
  bf16* sOw = smem + w * 4352;  // 32 rows x 136 stride (17408 elems total <= 25600)
#pragma unroll
  for (int nt = 0; nt < 2; ++nt) {
    const float inv = 1.0f / lrow[nt];
#pragma unroll
    for (int mt = 0; mt < 8; ++mt) {
      bh4 pk;
#pragma unroll
      for (int r = 0; r < 4; ++r) pk.v[r] = (bf16)(o[mt][nt][r] * inv);
      *(bh4*)&sOw[(nt * 16 + l16) * 136 + mt * 16 + quad * 4] = pk;
    }
  }
  // same-wave write->read: lgkmcnt ordering suffices, no barrier
  {
    const int col = (lane & 15) * 8;
#pragma unroll
    for (int p = 0; p < 8; ++p) {
      const int row = p * 4 + (lane >> 4);
      int4 v = *(const int4*)&sOw[row * 136 + col];
      const int token = qt * 128 + w * 32 + row;
      *(int4*)(Y + ((size_t)(b * 2048 + token)) * 2048 + h * 128 + col) = v;
    }
  }
}

extern "C" void kernel_launch(void* const* d_in, const int* in_sizes, int n_in,
                              void* d_out, int out_size, void* d_ws, size_t ws_size,
                              hipStream_t stream) {
  const float* x_raw  = (const float*)d_in[0];
  const int*   mask   = (const int*)d_in[1];
  const float* wq_raw = (const float*)d_in[2];
  const float* wo_raw = (const float*)d_in[3];
  float* out = (float*)d_out;  // reference output dtype is fp32

  char* ws = (char*)d_ws;
  const size_t MB = 1024 * 1024;
  bf16* xb  = (bf16*)(ws + 256);              // 32 MiB  (x bf16; later reused as yb)
  bf16* wqb = (bf16*)(ws + 256 + 32 * MB);    // 24 MiB  (w_qkv bf16; later reused as wob)
  bf16* qb  = (bf16*)(ws + 256 + 56 * MB);    // 32 MiB  (B,H,T,HD) pre-scaled
  bf16* kb  = (bf16*)(ws + 256 + 88 * MB);    // 32 MiB  (B,H,T,HD)
  bf16* vt  = (bf16*)(ws + 256 + 120 * MB);   // 32 MiB  (B,H,HD,T)
  bf16* yb  = xb;                             // attention output (B,T,D)
  bf16* wob = wqb;                            // w_o bf16 (converted after gemm1)

  convert_to_bf16<<<1024, 256, 0, stream>>>(x_raw, xb, (long)in_sizes[0]);
  convert_to_bf16<<<1024, 256, 0, stream>>>(wq_raw, wqb, (long)in_sizes[2]);

  // qkv projection (M=8192, N=6144, K=2048), scatter to per-head layouts
  gemm_bt<0><<<dim3(48, 64), 256, 0, stream>>>(xb, wqb, qb, kb, vt, 8192, 6144, 2048);

  // w_o conversion (overwrites wqb region — dead after gemm1)
  convert_to_bf16<<<1024, 256, 0, stream>>>(wo_raw, wob, (long)in_sizes[3]);

  // fused flash attention (writes yb = xb region — x dead after gemm1)
  attn_kernel<<<dim3(64, 16), 256, 0, stream>>>(qb, kb, vt, mask, yb);

  // output projection (M=8192, N=2048, K=2048), fp32 out
  gemm_bt<1><<<dim3(16, 64), 256, 0, stream>>>(yb, wob, out, nullptr, nullptr, 8192, 2048, 2048);
}

// Round 4
// 632.540 us; speedup vs baseline: 1.8740x; 1.0603x over previous
//
#include <hip/hip_runtime.h>
#include <hip/hip_bf16.h>

typedef __bf16 bf16;
typedef bf16 bf16x8 __attribute__((ext_vector_type(8)));
typedef float f32x4 __attribute__((ext_vector_type(4)));

struct alignas(8) bh4 { bf16 v[4]; };

// async global->LDS, 16B per lane. LDS dest must be wave-uniform base + lane*16.
__device__ __forceinline__ void glds16(const bf16* g, bf16* l) {
  __builtin_amdgcn_global_load_lds(
      (const __attribute__((address_space(1))) void*)g,
      (__attribute__((address_space(3))) void*)l, 16, 0, 0);
}

// log2(e) / sqrt(128): folded into Q so softmax uses exp2 (native v_exp_f32)
#define QSCALE (1.4426950408889634f / 11.313708498984761f)
// defer-max threshold (log2 domain)
#define DEFER_THR 8.0f

// fp32 -> bf16 conversion (inputs are fp32).
__global__ void convert_to_bf16(const float* __restrict__ s, bf16* __restrict__ dst,
                                long n) {
  const long stride = (long)gridDim.x * blockDim.x * 8;
  for (long i = ((long)blockIdx.x * blockDim.x + threadIdx.x) * 8; i < n; i += stride) {
    float4 a = *(const float4*)(s + i);
    float4 b = *(const float4*)(s + i + 4);
    bf16x8 o;
    o[0] = (bf16)a.x; o[1] = (bf16)a.y; o[2] = (bf16)a.z; o[3] = (bf16)a.w;
    o[4] = (bf16)b.x; o[5] = (bf16)b.y; o[6] = (bf16)b.z; o[7] = (bf16)b.w;
    *(bf16x8*)(dst + i) = o;
  }
}

// ---------------- GEMM: C = A (M,K) * Bw^T, Bw is (N,K) row-major ----------
// Round-4: 256x256 tile, BK=64, 512 thr (8 waves 2Mx4N), double-buffered LDS
// (128 KB), 4 quadrant-phases per K-tile with raw s_barrier + lgkmcnt(0) +
// setprio around MFMA clusters (T3/T4/T5), XOR chunk swizzle on LDS (T2,
// both-sides: pre-swizzled glds16 source + swizzled ds_read), XCD-aware
// block swizzle (T1). Next K-tile staged in phase Q0 into the other buffer
// (that buffer's readers finished before the previous boundary barrier ->
// race-free); boundary vmcnt(0) covers loads issued ~3 phases earlier.
// Lessons kept: no loop-spanning register prefetch (r1); single uniform
// control flow, no duplicated hot bodies (r2).
template <int MODE>
__global__ __launch_bounds__(512, 2)
void gemm256(const bf16* __restrict__ A, const bf16* __restrict__ Bw,
             void* __restrict__ C0v, bf16* __restrict__ C1,
             bf16* __restrict__ C2, int M, int N, int K) {
  __shared__ __align__(16) bf16 sA[2][256 * 64];  // 64 KB
  __shared__ __align__(16) bf16 sB[2][256 * 64];  // 64 KB
  const int tid = threadIdx.x;
  const int lane = tid & 63;
  const int wid = tid >> 6;
  const int wm = wid >> 2, wn = wid & 3;  // 2 x 4 wave grid
  const int quad = lane >> 4, l16 = lane & 15;

  // XCD-aware bijective block swizzle (grid counts here are multiples of 8)
  const int gx = gridDim.x;
  const int nwg = gx * gridDim.y;
  const int bid0 = blockIdx.y * gx + blockIdx.x;
  const int cpx = nwg >> 3;
  const int bid = (bid0 & 7) * cpx + (bid0 >> 3);
  const int bm = (bid / gx) * 256, bn = (bid % gx) * 256;

  f32x4 acc[8][4] = {};

  // prologue: stage K-tile 0 into buffer 0 (source pre-swizzled: chunk cp of
  // row holds global chunk cp^(row&7); LDS dest linear per glds16 contract)
#pragma unroll
  for (int r = 0; r < 4; ++r) {
    const int idx = r * 512 + tid;
    const int row = idx >> 3, cp = idx & 7;
    const int cs = cp ^ (row & 7);
    glds16(A + (size_t)(bm + row) * K + cs * 8, &sA[0][idx * 8]);
    glds16(Bw + (size_t)(bn + row) * K + cs * 8, &sB[0][idx * 8]);
  }
  asm volatile("s_waitcnt vmcnt(0)" ::: "memory");
  __builtin_amdgcn_s_barrier();

  const int NT = K >> 6;
  for (int kt = 0; kt < NT; ++kt) {
    const bf16* cA = sA[kt & 1];
    const bf16* cB = sB[kt & 1];
    bf16x8 af[4][2];           // A fragments for current row-half (mt x ksub)
    bf16x8 bfA[2][2], bfB[2][2];  // B fragments: col-tiles 0-1 and 2-3

    // ---------- phase Q0: rows-lo x cols-lo ----------
#pragma unroll
    for (int mt = 0; mt < 4; ++mt) {
      const int R = wm * 128 + mt * 16 + l16;
#pragma unroll
      for (int s = 0; s < 2; ++s)
        af[mt][s] = *(const bf16x8*)&cA[R * 64 + (((s * 4 + quad) ^ (R & 7)) * 8)];
    }
#pragma unroll
    for (int nt = 0; nt < 2; ++nt) {
      const int R = wn * 64 + nt * 16 + l16;
#pragma unroll
      for (int s = 0; s < 2; ++s)
        bfA[nt][s] = *(const bf16x8*)&cB[R * 64 + (((s * 4 + quad) ^ (R & 7)) * 8)];
    }
    if (kt + 1 < NT) {  // stage next K-tile into the other buffer (DMA)
      bf16* nA = (bf16*)sA[(kt + 1) & 1];
      bf16* nB = (bf16*)sB[(kt + 1) & 1];
      const int k0 = (kt + 1) << 6;
#pragma unroll
      for (int r = 0; r < 4; ++r) {
        const int idx = r * 512 + tid;
        const int row = idx >> 3, cp = idx & 7;
        const int cs = cp ^ (row & 7);
        glds16(A + (size_t)(bm + row) * K + k0 + cs * 8, &nA[idx * 8]);
        glds16(Bw + (size_t)(bn + row) * K + k0 + cs * 8, &nB[idx * 8]);
      }
    }
    __builtin_amdgcn_s_barrier();
    asm volatile("s_waitcnt lgkmcnt(0)" ::: "memory");
    __builtin_amdgcn_sched_barrier(0);
    __builtin_amdgcn_s_setprio(1);
#pragma unroll
    for (int mt = 0; mt < 4; ++mt)
#pragma unroll
      for (int nt = 0; nt < 2; ++nt)
#pragma unroll
        for (int s = 0; s < 2; ++s)
          acc[mt][nt] = __builtin_amdgcn_mfma_f32_16x16x32_bf16(af[mt][s], bfA[nt][s], acc[mt][nt], 0, 0, 0);
    __builtin_amdgcn_s_setprio(0);
    __builtin_amdgcn_s_barrier();

    // ---------- phase Q1: rows-lo x cols-hi ----------
#pragma unroll
    for (int nt = 0; nt < 2; ++nt) {
      const int R = wn * 64 + (2 + nt) * 16 + l16;
#pragma unroll
      for (int s = 0; s < 2; ++s)
        bfB[nt][s] = *(const bf16x8*)&cB[R * 64 + (((s * 4 + quad) ^ (R & 7)) * 8)];
    }
    __builtin_amdgcn_s_barrier();
    asm volatile("s_waitcnt lgkmcnt(0)" ::: "memory");
    __builtin_amdgcn_sched_barrier(0);
    __builtin_amdgcn_s_setprio(1);
#pragma unroll
    for (int mt = 0; mt < 4; ++mt)
#pragma unroll
      for (int nt = 0; nt < 2; ++nt)
#pragma unroll
        for (int s = 0; s < 2; ++s)
          acc[mt][2 + nt] = __builtin_amdgcn_mfma_f32_16x16x32_bf16(af[mt][s], bfB[nt][s], acc[mt][2 + nt], 0, 0, 0);
    __builtin_amdgcn_s_setprio(0);
    __builtin_amdgcn_s_barrier();

    // ---------- phase Q2: rows-hi x cols-lo ----------
#pragma unroll
    for (int mt = 0; mt < 4; ++mt) {
      const int R = wm * 128 + 64 + mt * 16 + l16;
#pragma unroll
      for (int s = 0; s < 2; ++s)
        af[mt][s] = *(const bf16x8*)&cA[R * 64 + (((s * 4 + quad) ^ (R & 7)) * 8)];
    }
    __builtin_amdgcn_s_barrier();
    asm volatile("s_waitcnt lgkmcnt(0)" ::: "memory");
    __builtin_amdgcn_sched_barrier(0);
    __builtin_amdgcn_s_setprio(1);
#pragma unroll
    for (int mt = 0; mt < 4; ++mt)
#pragma unroll
      for (int nt = 0; nt < 2; ++nt)
#pragma unroll
        for (int s = 0; s < 2; ++s)
          acc[4 + mt][nt] = __builtin_amdgcn_mfma_f32_16x16x32_bf16(af[mt][s], bfA[nt][s], acc[4 + mt][nt], 0, 0, 0);
    __builtin_amdgcn_s_setprio(0);
    __builtin_amdgcn_s_barrier();

    // ---------- phase Q3: rows-hi x cols-hi; boundary ----------
    __builtin_amdgcn_s_setprio(1);
#pragma unroll
    for (int mt = 0; mt < 4; ++mt)
#pragma unroll
      for (int nt = 0; nt < 2; ++nt)
#pragma unroll
        for (int s = 0; s < 2; ++s)
          acc[4 + mt][2 + nt] = __builtin_amdgcn_mfma_f32_16x16x32_bf16(af[mt][s], bfB[nt][s], acc[4 + mt][2 + nt], 0, 0, 0);
    __builtin_amdgcn_s_setprio(0);
    // boundary: my staged loads (issued ~3 phases ago) must be in LDS before
    // anyone reads next tile; everyone's reads of this tile are done at the
    // barrier.
    asm volatile("s_waitcnt vmcnt(0)" ::: "memory");
    __builtin_amdgcn_s_barrier();
  }

  // ---------------- epilogue ----------------
  if (MODE == 0) {
    bf16* C0 = (bf16*)C0v;
#pragma unroll
    for (int i = 0; i < 8; ++i) {
      const int m0 = bm + wm * 128 + i * 16 + quad * 4;
      const int b = m0 >> 11, t0 = m0 & 2047;
#pragma unroll
      for (int j = 0; j < 4; ++j) {
        const int ncol = bn + wn * 64 + j * 16 + l16;
        const int which = ncol >> 11;       // block-uniform (bn 256-aligned)
        const int d = ncol & 2047;
        const int h = d >> 7, hd = d & 127;
        if (which == 0) {
          bf16* dst = C0 + (((size_t)(b * 16 + h) * 2048 + t0) * 128 + hd);
#pragma unroll
          for (int r = 0; r < 4; ++r) dst[(size_t)r * 128] = (bf16)(acc[i][j][r] * QSCALE);
        } else if (which == 1) {
          bf16* dst = C1 + (((size_t)(b * 16 + h) * 2048 + t0) * 128 + hd);
#pragma unroll
          for (int r = 0; r < 4; ++r) dst[(size_t)r * 128] = (bf16)acc[i][j][r];
        } else {
          bh4 pk;
#pragma unroll
          for (int r = 0; r < 4; ++r) pk.v[r] = (bf16)acc[i][j][r];
          *(bh4*)(C2 + ((size_t)((b * 16 + h) * 128 + hd) * 2048 + t0)) = pk;
        }
      }
    }
  } else {
    float* C0 = (float*)C0v;  // fp32 final output
#pragma unroll
    for (int i = 0; i < 8; ++i) {
      const int m0 = bm + wm * 128 + i * 16 + quad * 4;
#pragma unroll
      for (int j = 0; j < 4; ++j) {
        const int n = bn + wn * 64 + j * 16 + l16;
#pragma unroll
        for (int r = 0; r < 4; ++r)
          C0[(size_t)(m0 + r) * N + n] = acc[i][j][r];
      }
    }
  }
}

// ---------------- Flash attention, transposed-S formulation ----------------
// (round-3 version, unchanged: single softmax path, mask bitmap cold path,
// defer-max; 84 VGPR, zero scratch)
__global__ __launch_bounds__(256, 3)
void attn_kernel(const bf16* __restrict__ Q, const bf16* __restrict__ Kb,
                 const bf16* __restrict__ Vt, const int* __restrict__ mask,
                 bf16* __restrict__ Y) {
  __shared__ __align__(16) bf16 smem[25600];  // 51200 B
  bf16* sK = smem;                 // 64 keys x 128 hd (swizzled chunks), 16 KB
  bf16* sV = smem + 8192;          // 128 hd x 64 keys (swizzled chunks), 16 KB
  bf16* sP = smem + 16384;         // per-wave 32 queries x 72 (pad), 18 KB

  const int tid = threadIdx.x;
  const int lane = tid & 63, w = tid >> 6;
  const int quad = lane >> 4, l16 = lane & 15;
  const int bh = blockIdx.x, b = bh >> 4, h = bh & 15;
  const int qt = blockIdx.y;
  const size_t head = (size_t)bh * (2048 * 128);

  // Q fragments resident: B-operand layout (lane = query, k = quad*8+j)
  bf16x8 qf[2][4];
#pragma unroll
  for (int nt = 0; nt < 2; ++nt) {
    const int t = qt * 128 + w * 32 + nt * 16 + l16;
    const bf16* g = Q + head + (size_t)t * 128 + quad * 8;
#pragma unroll
    for (int kk = 0; kk < 4; ++kk)
      qf[nt][kk] = *(const bf16x8*)(g + kk * 32);
  }

  f32x4 o[8][2] = {};                       // O^T: rows hd (8 tiles), cols query
  float mrow[2] = {-3.0e38f, -3.0e38f};
  float lrow[2] = {0.0f, 0.0f};

  const int* maskb = mask + b * 2048;
  bf16* sPw = sP + w * (32 * 72);

  // per-key-tile validity bitmap: lane l checks keys [l*32, l*32+32); tile kt
  // (64 keys) is fully valid iff bits 2kt and 2kt+1 are both set.
  unsigned long long vmask;
  {
    const int4* mp4 = (const int4*)maskb;
    bool ok = true;
#pragma unroll
    for (int j = 0; j < 8; ++j) {
      const int4 q4 = mp4[lane * 8 + j];
      ok = ok && (q4.x != 0) && (q4.y != 0) && (q4.z != 0) && (q4.w != 0);
    }
    vmask = __ballot(ok);
  }

  for (int kt = 0; kt < 32; ++kt) {
    const int key0 = kt * 64;
    {  // stage K tile (64 keys x 128 hd = 16 chunks/row), swizzled
      const int cp = lane & 15;
      const int rbase = w * 16 + (lane >> 4);
#pragma unroll
      for (int p = 0; p < 4; ++p) {
        const int row = rbase + p * 4;
        const int c = (cp & 8) | ((cp ^ row) & 7);
        glds16(Kb + head + (size_t)(key0 + row) * 128 + c * 8,
               &sK[(w * 16 + p * 4) * 128 + lane * 8]);
      }
    }
    {  // stage V^T tile (128 hd x 64 keys = 8 chunks/row), swizzled
      const int cp = lane & 7;
      const int rbase = w * 32 + (lane >> 3);
#pragma unroll
      for (int p = 0; p < 4; ++p) {
        const int row = rbase + p * 8;
        const int c = cp ^ (row & 7);
        glds16(Vt + head + (size_t)row * 2048 + key0 + c * 8,
               &sV[(w * 32 + p * 8) * 64 + lane * 8]);
      }
    }
    __syncthreads();

    // S^T = K · Q^T : st[mt=key-tile][nt=query-tile]
    f32x4 st[4][2] = {};
#pragma unroll
    for (int kk = 0; kk < 4; ++kk) {
      bf16x8 ak[4];
#pragma unroll
      for (int mt = 0; mt < 4; ++mt) {
        const int row = mt * 16 + l16;
        const int c = kk * 4 + quad;
        const int cp = (c & 8) | ((c ^ row) & 7);
        ak[mt] = *(const bf16x8*)&sK[row * 128 + cp * 8];
      }
#pragma unroll
      for (int mt = 0; mt < 4; ++mt)
#pragma unroll
        for (int nt = 0; nt < 2; ++nt)
          st[mt][nt] = __builtin_amdgcn_mfma_f32_16x16x32_bf16(ak[mt], qf[nt][kk], st[mt][nt], 0, 0, 0);
    }

    // cold path: partially-masked tile -> neutralize masked keys in place.
    if (((vmask >> (2 * kt)) & 3ULL) != 3ULL) {
#pragma unroll
      for (int mt = 0; mt < 4; ++mt) {
#pragma unroll
        for (int r = 0; r < 4; ++r) {
          const int mk = maskb[key0 + mt * 16 + quad * 4 + r];
#pragma unroll
          for (int nt = 0; nt < 2; ++nt)
            if (mk == 0) { st[mt][nt][r] = -1.0e30f; }
        }
      }
    }

    // single softmax path, defer-max (T13)
#pragma unroll
    for (int nt = 0; nt < 2; ++nt) {
      float mx = -1.0e30f;
#pragma unroll
      for (int mt = 0; mt < 4; ++mt)
#pragma unroll
        for (int r = 0; r < 4; ++r) mx = fmaxf(mx, st[mt][nt][r]);
      mx = fmaxf(mx, __shfl_xor(mx, 16));
      mx = fmaxf(mx, __shfl_xor(mx, 32));
      if (!__all(mx <= mrow[nt] + DEFER_THR)) {
        const float newm = fmaxf(mrow[nt], mx);
        const float alpha = exp2f(mrow[nt] - newm);
        mrow[nt] = newm;
        lrow[nt] *= alpha;
#pragma unroll
        for (int mt = 0; mt < 8; ++mt)
#pragma unroll
          for (int r = 0; r < 4; ++r) o[mt][nt][r] *= alpha;
      }
      const float m = mrow[nt];
      float rs = 0.0f;
#pragma unroll
      for (int mt = 0; mt < 4; ++mt) {
        bh4 pk;
#pragma unroll
        for (int r = 0; r < 4; ++r) {
          const float p = exp2f(st[mt][nt][r] - m);
          rs += p;
          pk.v[r] = (bf16)p;
        }
        *(bh4*)&sPw[(nt * 16 + l16) * 72 + mt * 16 + quad * 4] = pk;
      }
      rs += __shfl_xor(rs, 16);
      rs += __shfl_xor(rs, 32);
      lrow[nt] += rs;
    }

    // O^T += V^T · P^T  (wave-local sP: same-wave ds ordering suffices)
#pragma unroll
    for (int kk = 0; kk < 2; ++kk) {
      bf16x8 bp[2];
#pragma unroll
      for (int nt = 0; nt < 2; ++nt)
        bp[nt] = *(const bf16x8*)&sPw[(nt * 16 + l16) * 72 + kk * 32 + quad * 8];
#pragma unroll
      for (int mt = 0; mt < 8; ++mt) {
        const int row = mt * 16 + l16;
        const int c = kk * 4 + quad;
        bf16x8 av = *(const bf16x8*)&sV[row * 64 + (c ^ (row & 7)) * 8];
#pragma unroll
        for (int nt = 0; nt < 2; ++nt)
          o[mt][nt] = __builtin_amdgcn_mfma_f32_16x16x32_bf16(av, bp[nt], o[mt][nt], 0, 0, 0);
      }
    }
    __syncthreads();  // sK/sV reads done before next staging
  }

  // epilogue: normalize, transpose O^T->O via per-wave LDS region, 16B stores
  bf16* sOw = smem + w * 4352;  // 32 rows x 136 stride
#pragma unroll
  for (int nt = 0; nt < 2; ++nt) {
    const float inv = 1.0f / lrow[nt];
#pragma unroll
    for (int mt = 0; mt < 8; ++mt) {
      bh4 pk;
#pragma unroll
      for (int r = 0; r < 4; ++r) pk.v[r] = (bf16)(o[mt][nt][r] * inv);
      *(bh4*)&sOw[(nt * 16 + l16) * 136 + mt * 16 + quad * 4] = pk;
    }
  }
  // same-wave write->read: lgkmcnt ordering suffices, no barrier
  {
    const int col = (lane & 15) * 8;
#pragma unroll
    for (int p = 0; p < 8; ++p) {
      const int row = p * 4 + (lane >> 4);
      int4 v = *(const int4*)&sOw[row * 136 + col];
      const int token = qt * 128 + w * 32 + row;
      *(int4*)(Y + ((size_t)(b * 2048 + token)) * 2048 + h * 128 + col) = v;
    }
  }
}

extern "C" void kernel_launch(void* const* d_in, const int* in_sizes, int n_in,
                              void* d_out, int out_size, void* d_ws, size_t ws_size,
                              hipStream_t stream) {
  const float* x_raw  = (const float*)d_in[0];
  const int*   mask   = (const int*)d_in[1];
  const float* wq_raw = (const float*)d_in[2];
  const float* wo_raw = (const float*)d_in[3];
  float* out = (float*)d_out;  // reference output dtype is fp32

  char* ws = (char*)d_ws;
  const size_t MB = 1024 * 1024;
  bf16* xb  = (bf16*)(ws + 256);              // 32 MiB  (x bf16; later reused as yb)
  bf16* wqb = (bf16*)(ws + 256 + 32 * MB);    // 24 MiB  (w_qkv bf16; later reused as wob)
  bf16* qb  = (bf16*)(ws + 256 + 56 * MB);    // 32 MiB  (B,H,T,HD) pre-scaled
  bf16* kb  = (bf16*)(ws + 256 + 88 * MB);    // 32 MiB  (B,H,T,HD)
  bf16* vt  = (bf16*)(ws + 256 + 120 * MB);   // 32 MiB  (B,H,HD,T)
  bf16* yb  = xb;                             // attention output (B,T,D)
  bf16* wob = wqb;                            // w_o bf16 (converted after gemm1)

  convert_to_bf16<<<1024, 256, 0, stream>>>(x_raw, xb, (long)in_sizes[0]);
  convert_to_bf16<<<1024, 256, 0, stream>>>(wq_raw, wqb, (long)in_sizes[2]);

  // qkv projection (M=8192, N=6144, K=2048), scatter to per-head layouts
  gemm256<0><<<dim3(24, 32), 512, 0, stream>>>(xb, wqb, qb, kb, vt, 8192, 6144, 2048);

  // w_o conversion (overwrites wqb region — dead after gemm1)
  convert_to_bf16<<<1024, 256, 0, stream>>>(wo_raw, wob, (long)in_sizes[3]);

  // fused flash attention (writes yb = xb region — x dead after gemm1)
  attn_kernel<<<dim3(64, 16), 256, 0, stream>>>(qb, kb, vt, mask, yb);

  // output projection (M=8192, N=2048, K=2048), fp32 out
  gemm256<1><<<dim3(8, 32), 512, 0, stream>>>(yb, wob, out, nullptr, nullptr, 8192, 2048, 2048);
}

// Round 5
// 606.508 us; speedup vs baseline: 1.9544x; 1.0429x over previous
//
#include <hip/hip_runtime.h>
#include <hip/hip_bf16.h>

typedef __bf16 bf16;
typedef bf16 bf16x8 __attribute__((ext_vector_type(8)));
typedef float f32x4 __attribute__((ext_vector_type(4)));

struct alignas(8) bh4 { bf16 v[4]; };

// async global->LDS, 16B per lane. LDS dest must be wave-uniform base + lane*16.
__device__ __forceinline__ void glds16(const bf16* g, bf16* l) {
  __builtin_amdgcn_global_load_lds(
      (const __attribute__((address_space(1))) void*)g,
      (__attribute__((address_space(3))) void*)l, 16, 0, 0);
}

// log2(e) / sqrt(128): folded into Q so softmax uses exp2 (native v_exp_f32)
#define QSCALE (1.4426950408889634f / 11.313708498984761f)
// defer-max threshold (log2 domain)
#define DEFER_THR 8.0f

// fp32 -> bf16 conversion (inputs are fp32).
__global__ void convert_to_bf16(const float* __restrict__ s, bf16* __restrict__ dst,
                                long n) {
  const long stride = (long)gridDim.x * blockDim.x * 8;
  for (long i = ((long)blockIdx.x * blockDim.x + threadIdx.x) * 8; i < n; i += stride) {
    float4 a = *(const float4*)(s + i);
    float4 b = *(const float4*)(s + i + 4);
    bf16x8 o;
    o[0] = (bf16)a.x; o[1] = (bf16)a.y; o[2] = (bf16)a.z; o[3] = (bf16)a.w;
    o[4] = (bf16)b.x; o[5] = (bf16)b.y; o[6] = (bf16)b.z; o[7] = (bf16)b.w;
    *(bf16x8*)(dst + i) = o;
  }
}

// ---------------- GEMM: C = A (M,K) * Bw^T, Bw is (N,K) row-major ----------
// Round-5: m201-style counted-vmcnt pipeline. 256x256 tile, BK=64, 512 thr
// (8 waves 2Mx4N), double-buffered LDS split into consumption-aligned
// HALF-TILES:
//   A-half hh = rows with bit6==hh ({0-63,128-191} / {64-127,192-255})
//   B-half hh = rows with bit5==hh
// so every wave reads A0,B0 only in Q0, B1 in Q1, A1 in Q2. One half-tile
// staged per phase (2 glds16/thread), stream order per tile [A0,B0,B1,A1],
// staged 4-7 half-tiles ahead. Boundary wait = vmcnt(6) (3 half-tiles in
// flight across the barrier; m218 lever), vmcnt(0) only at the last two
// boundaries. Stage targets are free: region's last reader finished its
// lgkmcnt(0)+MFMA before the barrier that precedes the stage issue.
// T2 XOR chunk swizzle both-sides (verified round 4: 0 bank conflicts),
// T5 setprio, T1 bijective XCD swizzle.
// Lessons kept: no loop-spanning register prefetch (r1: scratch spill);
// single uniform control flow (r2).
template <int MODE>
__global__ __launch_bounds__(512, 2)
void gemm256(const bf16* __restrict__ A, const bf16* __restrict__ Bw,
             void* __restrict__ C0v, bf16* __restrict__ C1,
             bf16* __restrict__ C2, int M, int N, int K) {
  __shared__ __align__(16) bf16 sA[2][2][128 * 64];  // [buf][half] 64 KB
  __shared__ __align__(16) bf16 sB[2][2][128 * 64];  // [buf][half] 64 KB
  const int tid = threadIdx.x;
  const int lane = tid & 63;
  const int wid = tid >> 6;
  const int wm = wid >> 2, wn = wid & 3;  // 2 x 4 wave grid
  const int quad = lane >> 4, l16 = lane & 15;

  // XCD-aware bijective block swizzle (grid counts here are multiples of 8)
  const int gx = gridDim.x;
  const int nwg = gx * gridDim.y;
  const int bid0 = blockIdx.y * gx + blockIdx.x;
  const int cpx = nwg >> 3;
  const int bid = (bid0 & 7) * cpx + (bid0 >> 3);
  const int bm = (bid / gx) * 256, bn = (bid % gx) * 256;

  f32x4 acc[8][4] = {};

  // per-thread staging constants (identical both glds16 rounds of a half-tile)
  const int s_r = tid >> 3;                          // local row 0..63
  const int s_cs = ((tid & 7) ^ (s_r & 7)) * 8;      // pre-swizzled src chunk
  const int grB0 = ((s_r >> 5) << 6) + (s_r & 31);   // B row base (bit5 gap)

  // stage one 128x64 half-tile (2 x glds16/thread, rows lr and lr+64)
  auto stageA = [&](int bufi, int hh, int ktile) {
    const int k0 = ktile << 6;
    bf16* dst = &sA[bufi][hh][0] + tid * 8;
    const bf16* src = A + (size_t)(bm + hh * 64 + s_r) * K + k0 + s_cs;
    glds16(src, dst);                       // lr = s_r        -> row hh*64+s_r
    glds16(src + (size_t)128 * K, dst + 4096);  // lr = 64+s_r -> row 128+hh*64+s_r
  };
  auto stageB = [&](int bufi, int hh, int ktile) {
    const int k0 = ktile << 6;
    bf16* dst = &sB[bufi][hh][0] + tid * 8;
    const bf16* src = Bw + (size_t)(bn + hh * 32 + grB0) * K + k0 + s_cs;
    glds16(src, dst);
    glds16(src + (size_t)128 * K, dst + 4096);
  };

  const int NT = K >> 6;
  // prologue: half-tile stream indices 0..6 (tile0 all, tile1 A0,B0,B1)
  stageA(0, 0, 0);
  stageB(0, 0, 0);
  stageB(0, 1, 0);
  stageA(0, 1, 0);
  stageA(1, 0, 1);
  stageB(1, 0, 1);
  stageB(1, 1, 1);
  asm volatile("s_waitcnt vmcnt(6)" ::: "memory");  // tile0 (oldest 8) landed
  __builtin_amdgcn_s_barrier();

  for (int kt = 0; kt < NT; ++kt) {
    const int buf = kt & 1;
    bf16x8 af[4][2], bfA[2][2], bfB[2][2];

    // ---------- Q0: read A0,B0; stage A1(kt+1); rows-lo x cols-lo ----------
#pragma unroll
    for (int mt = 0; mt < 4; ++mt) {
      const int lr = wm * 64 + mt * 16 + l16;
#pragma unroll
      for (int s = 0; s < 2; ++s)
        af[mt][s] = *(const bf16x8*)&sA[buf][0][lr * 64 + (((s * 4 + quad) ^ (lr & 7)) * 8)];
    }
#pragma unroll
    for (int nt = 0; nt < 2; ++nt) {
      const int lr = wn * 32 + nt * 16 + l16;
#pragma unroll
      for (int s = 0; s < 2; ++s)
        bfA[nt][s] = *(const bf16x8*)&sB[buf][0][lr * 64 + (((s * 4 + quad) ^ (lr & 7)) * 8)];
    }
    if (kt + 1 < NT) stageA(buf ^ 1, 1, kt + 1);
    __builtin_amdgcn_s_barrier();
    asm volatile("s_waitcnt lgkmcnt(0)" ::: "memory");
    __builtin_amdgcn_sched_barrier(0);
    __builtin_amdgcn_s_setprio(1);
#pragma unroll
    for (int mt = 0; mt < 4; ++mt)
#pragma unroll
      for (int nt = 0; nt < 2; ++nt)
#pragma unroll
        for (int s = 0; s < 2; ++s)
          acc[mt][nt] = __builtin_amdgcn_mfma_f32_16x16x32_bf16(af[mt][s], bfA[nt][s], acc[mt][nt], 0, 0, 0);
    __builtin_amdgcn_s_setprio(0);
    __builtin_amdgcn_s_barrier();

    // ---------- Q1: read B1; stage A0(kt+2); rows-lo x cols-hi ----------
#pragma unroll
    for (int nt = 0; nt < 2; ++nt) {
      const int lr = wn * 32 + nt * 16 + l16;
#pragma unroll
      for (int s = 0; s < 2; ++s)
        bfB[nt][s] = *(const bf16x8*)&sB[buf][1][lr * 64 + (((s * 4 + quad) ^ (lr & 7)) * 8)];
    }
    if (kt + 2 < NT) stageA(buf, 0, kt + 2);
    __builtin_amdgcn_s_barrier();
    asm volatile("s_waitcnt lgkmcnt(0)" ::: "memory");
    __builtin_amdgcn_sched_barrier(0);
    __builtin_amdgcn_s_setprio(1);
#pragma unroll
    for (int mt = 0; mt < 4; ++mt)
#pragma unroll
      for (int nt = 0; nt < 2; ++nt)
#pragma unroll
        for (int s = 0; s < 2; ++s)
          acc[mt][2 + nt] = __builtin_amdgcn_mfma_f32_16x16x32_bf16(af[mt][s], bfB[nt][s], acc[mt][2 + nt], 0, 0, 0);
    __builtin_amdgcn_s_setprio(0);
    __builtin_amdgcn_s_barrier();

    // ---------- Q2: read A1; stage B0(kt+2); rows-hi x cols-lo ----------
#pragma unroll
    for (int mt = 0; mt < 4; ++mt) {
      const int lr = wm * 64 + mt * 16 + l16;
#pragma unroll
      for (int s = 0; s < 2; ++s)
        af[mt][s] = *(const bf16x8*)&sA[buf][1][lr * 64 + (((s * 4 + quad) ^ (lr & 7)) * 8)];
    }
    if (kt + 2 < NT) stageB(buf, 0, kt + 2);
    __builtin_amdgcn_s_barrier();
    asm volatile("s_waitcnt lgkmcnt(0)" ::: "memory");
    __builtin_amdgcn_sched_barrier(0);
    __builtin_amdgcn_s_setprio(1);
#pragma unroll
    for (int mt = 0; mt < 4; ++mt)
#pragma unroll
      for (int nt = 0; nt < 2; ++nt)
#pragma unroll
        for (int s = 0; s < 2; ++s)
          acc[4 + mt][nt] = __builtin_amdgcn_mfma_f32_16x16x32_bf16(af[mt][s], bfA[nt][s], acc[4 + mt][nt], 0, 0, 0);
    __builtin_amdgcn_s_setprio(0);
    __builtin_amdgcn_s_barrier();

    // ---------- Q3: stage B1(kt+2); rows-hi x cols-hi; boundary ----------
    if (kt + 2 < NT) stageB(buf, 1, kt + 2);
    __builtin_amdgcn_s_barrier();
    __builtin_amdgcn_s_setprio(1);
#pragma unroll
    for (int mt = 0; mt < 4; ++mt)
#pragma unroll
      for (int nt = 0; nt < 2; ++nt)
#pragma unroll
        for (int s = 0; s < 2; ++s)
          acc[4 + mt][2 + nt] = __builtin_amdgcn_mfma_f32_16x16x32_bf16(af[mt][s], bfB[nt][s], acc[4 + mt][2 + nt], 0, 0, 0);
    __builtin_amdgcn_s_setprio(0);
    if (kt < NT - 1) {
      // counted wait: tile kt+1's 4 half-tiles are the oldest beyond 6 loads;
      // the newest 3 (tile kt+2's A0,B0,B1) stay in flight across the barrier.
      if (kt < NT - 2) asm volatile("s_waitcnt vmcnt(6)" ::: "memory");
      else             asm volatile("s_waitcnt vmcnt(0)" ::: "memory");
      __builtin_amdgcn_s_barrier();
    }
  }

  // ---------------- epilogue ----------------
  if (MODE == 0) {
    bf16* C0 = (bf16*)C0v;
#pragma unroll
    for (int i = 0; i < 8; ++i) {
      const int m0 = bm + wm * 128 + i * 16 + quad * 4;
      const int b = m0 >> 11, t0 = m0 & 2047;
#pragma unroll
      for (int j = 0; j < 4; ++j) {
        const int ncol = bn + wn * 64 + j * 16 + l16;
        const int which = ncol >> 11;       // block-uniform (bn 256-aligned)
        const int d = ncol & 2047;
        const int h = d >> 7, hd = d & 127;
        if (which == 0) {
          bf16* dst = C0 + (((size_t)(b * 16 + h) * 2048 + t0) * 128 + hd);
#pragma unroll
          for (int r = 0; r < 4; ++r) dst[(size_t)r * 128] = (bf16)(acc[i][j][r] * QSCALE);
        } else if (which == 1) {
          bf16* dst = C1 + (((size_t)(b * 16 + h) * 2048 + t0) * 128 + hd);
#pragma unroll
          for (int r = 0; r < 4; ++r) dst[(size_t)r * 128] = (bf16)acc[i][j][r];
        } else {
          bh4 pk;
#pragma unroll
          for (int r = 0; r < 4; ++r) pk.v[r] = (bf16)acc[i][j][r];
          *(bh4*)(C2 + ((size_t)((b * 16 + h) * 128 + hd) * 2048 + t0)) = pk;
        }
      }
    }
  } else {
    float* C0 = (float*)C0v;  // fp32 final output
#pragma unroll
    for (int i = 0; i < 8; ++i) {
      const int m0 = bm + wm * 128 + i * 16 + quad * 4;
#pragma unroll
      for (int j = 0; j < 4; ++j) {
        const int n = bn + wn * 64 + j * 16 + l16;
#pragma unroll
        for (int r = 0; r < 4; ++r)
          C0[(size_t)(m0 + r) * N + n] = acc[i][j][r];
      }
    }
  }
}

// ---------------- Flash attention, transposed-S formulation ----------------
// (round-3 version, unchanged: single softmax path, mask bitmap cold path,
// defer-max; 84 VGPR, zero scratch)
__global__ __launch_bounds__(256, 3)
void attn_kernel(const bf16* __restrict__ Q, const bf16* __restrict__ Kb,
                 const bf16* __restrict__ Vt, const int* __restrict__ mask,
                 bf16* __restrict__ Y) {
  __shared__ __align__(16) bf16 smem[25600];  // 51200 B
  bf16* sK = smem;                 // 64 keys x 128 hd (swizzled chunks), 16 KB
  bf16* sV = smem + 8192;          // 128 hd x 64 keys (swizzled chunks), 16 KB
  bf16* sP = smem + 16384;         // per-wave 32 queries x 72 (pad), 18 KB

  const int tid = threadIdx.x;
  const int lane = tid & 63, w = tid >> 6;
  const int quad = lane >> 4, l16 = lane & 15;
  const int bh = blockIdx.x, b = bh >> 4, h = bh & 15;
  const int qt = blockIdx.y;
  const size_t head = (size_t)bh * (2048 * 128);

  // Q fragments resident: B-operand layout (lane = query, k = quad*8+j)
  bf16x8 qf[2][4];
#pragma unroll
  for (int nt = 0; nt < 2; ++nt) {
    const int t = qt * 128 + w * 32 + nt * 16 + l16;
    const bf16* g = Q + head + (size_t)t * 128 + quad * 8;
#pragma unroll
    for (int kk = 0; kk < 4; ++kk)
      qf[nt][kk] = *(const bf16x8*)(g + kk * 32);
  }

  f32x4 o[8][2] = {};                       // O^T: rows hd (8 tiles), cols query
  float mrow[2] = {-3.0e38f, -3.0e38f};
  float lrow[2] = {0.0f, 0.0f};

  const int* maskb = mask + b * 2048;
  bf16* sPw = sP + w * (32 * 72);

  // per-key-tile validity bitmap: lane l checks keys [l*32, l*32+32); tile kt
  // (64 keys) is fully valid iff bits 2kt and 2kt+1 are both set.
  unsigned long long vmask;
  {
    const int4* mp4 = (const int4*)maskb;
    bool ok = true;
#pragma unroll
    for (int j = 0; j < 8; ++j) {
      const int4 q4 = mp4[lane * 8 + j];
      ok = ok && (q4.x != 0) && (q4.y != 0) && (q4.z != 0) && (q4.w != 0);
    }
    vmask = __ballot(ok);
  }

  for (int kt = 0; kt < 32; ++kt) {
    const int key0 = kt * 64;
    {  // stage K tile (64 keys x 128 hd = 16 chunks/row), swizzled
      const int cp = lane & 15;
      const int rbase = w * 16 + (lane >> 4);
#pragma unroll
      for (int p = 0; p < 4; ++p) {
        const int row = rbase + p * 4;
        const int c = (cp & 8) | ((cp ^ row) & 7);
        glds16(Kb + head + (size_t)(key0 + row) * 128 + c * 8,
               &sK[(w * 16 + p * 4) * 128 + lane * 8]);
      }
    }
    {  // stage V^T tile (128 hd x 64 keys = 8 chunks/row), swizzled
      const int cp = lane & 7;
      const int rbase = w * 32 + (lane >> 3);
#pragma unroll
      for (int p = 0; p < 4; ++p) {
        const int row = rbase + p * 8;
        const int c = cp ^ (row & 7);
        glds16(Vt + head + (size_t)row * 2048 + key0 + c * 8,
               &sV[(w * 32 + p * 8) * 64 + lane * 8]);
      }
    }
    __syncthreads();

    // S^T = K · Q^T : st[mt=key-tile][nt=query-tile]
    f32x4 st[4][2] = {};
#pragma unroll
    for (int kk = 0; kk < 4; ++kk) {
      bf16x8 ak[4];
#pragma unroll
      for (int mt = 0; mt < 4; ++mt) {
        const int row = mt * 16 + l16;
        const int c = kk * 4 + quad;
        const int cp = (c & 8) | ((c ^ row) & 7);
        ak[mt] = *(const bf16x8*)&sK[row * 128 + cp * 8];
      }
#pragma unroll
      for (int mt = 0; mt < 4; ++mt)
#pragma unroll
        for (int nt = 0; nt < 2; ++nt)
          st[mt][nt] = __builtin_amdgcn_mfma_f32_16x16x32_bf16(ak[mt], qf[nt][kk], st[mt][nt], 0, 0, 0);
    }

    // cold path: partially-masked tile -> neutralize masked keys in place.
    if (((vmask >> (2 * kt)) & 3ULL) != 3ULL) {
#pragma unroll
      for (int mt = 0; mt < 4; ++mt) {
#pragma unroll
        for (int r = 0; r < 4; ++r) {
          const int mk = maskb[key0 + mt * 16 + quad * 4 + r];
#pragma unroll
          for (int nt = 0; nt < 2; ++nt)
            if (mk == 0) { st[mt][nt][r] = -1.0e30f; }
        }
      }
    }

    // single softmax path, defer-max (T13)
#pragma unroll
    for (int nt = 0; nt < 2; ++nt) {
      float mx = -1.0e30f;
#pragma unroll
      for (int mt = 0; mt < 4; ++mt)
#pragma unroll
        for (int r = 0; r < 4; ++r) mx = fmaxf(mx, st[mt][nt][r]);
      mx = fmaxf(mx, __shfl_xor(mx, 16));
      mx = fmaxf(mx, __shfl_xor(mx, 32));
      if (!__all(mx <= mrow[nt] + DEFER_THR)) {
        const float newm = fmaxf(mrow[nt], mx);
        const float alpha = exp2f(mrow[nt] - newm);
        mrow[nt] = newm;
        lrow[nt] *= alpha;
#pragma unroll
        for (int mt = 0; mt < 8; ++mt)
#pragma unroll
          for (int r = 0; r < 4; ++r) o[mt][nt][r] *= alpha;
      }
      const float m = mrow[nt];
      float rs = 0.0f;
#pragma unroll
      for (int mt = 0; mt < 4; ++mt) {
        bh4 pk;
#pragma unroll
        for (int r = 0; r < 4; ++r) {
          const float p = exp2f(st[mt][nt][r] - m);
          rs += p;
          pk.v[r] = (bf16)p;
        }
        *(bh4*)&sPw[(nt * 16 + l16) * 72 + mt * 16 + quad * 4] = pk;
      }
      rs += __shfl_xor(rs, 16);
      rs += __shfl_xor(rs, 32);
      lrow[nt] += rs;
    }

    // O^T += V^T · P^T  (wave-local sP: same-wave ds ordering suffices)
#pragma unroll
    for (int kk = 0; kk < 2; ++kk) {
      bf16x8 bp[2];
#pragma unroll
      for (int nt = 0; nt < 2; ++nt)
        bp[nt] = *(const bf16x8*)&sPw[(nt * 16 + l16) * 72 + kk * 32 + quad * 8];
#pragma unroll
      for (int mt = 0; mt < 8; ++mt) {
        const int row = mt * 16 + l16;
        const int c = kk * 4 + quad;
        bf16x8 av = *(const bf16x8*)&sV[row * 64 + (c ^ (row & 7)) * 8];
#pragma unroll
        for (int nt = 0; nt < 2; ++nt)
          o[mt][nt] = __builtin_amdgcn_mfma_f32_16x16x32_bf16(av, bp[nt], o[mt][nt], 0, 0, 0);
      }
    }
    __syncthreads();  // sK/sV reads done before next staging
  }

  // epilogue: normalize, transpose O^T->O via per-wave LDS region, 16B stores
  bf16* sOw = smem + w * 4352;  // 32 rows x 136 stride
#pragma unroll
  for (int nt = 0; nt < 2; ++nt) {
    const float inv = 1.0f / lrow[nt];
#pragma unroll
    for (int mt = 0; mt < 8; ++mt) {
      bh4 pk;
#pragma unroll
      for (int r = 0; r < 4; ++r) pk.v[r] = (bf16)(o[mt][nt][r] * inv);
      *(bh4*)&sOw[(nt * 16 + l16) * 136 + mt * 16 + quad * 4] = pk;
    }
  }
  // same-wave write->read: lgkmcnt ordering suffices, no barrier
  {
    const int col = (lane & 15) * 8;
#pragma unroll
    for (int p = 0; p < 8; ++p) {
      const int row = p * 4 + (lane >> 4);
      int4 v = *(const int4*)&sOw[row * 136 + col];
      const int token = qt * 128 + w * 32 + row;
      *(int4*)(Y + ((size_t)(b * 2048 + token)) * 2048 + h * 128 + col) = v;
    }
  }
}

extern "C" void kernel_launch(void* const* d_in, const int* in_sizes, int n_in,
                              void* d_out, int out_size, void* d_ws, size_t ws_size,
                              hipStream_t stream) {
  const float* x_raw  = (const float*)d_in[0];
  const int*   mask   = (const int*)d_in[1];
  const float* wq_raw = (const float*)d_in[2];
  const float* wo_raw = (const float*)d_in[3];
  float* out = (float*)d_out;  // reference output dtype is fp32

  char* ws = (char*)d_ws;
  const size_t MB = 1024 * 1024;
  bf16* xb  = (bf16*)(ws + 256);              // 32 MiB  (x bf16; later reused as yb)
  bf16* wqb = (bf16*)(ws + 256 + 32 * MB);    // 24 MiB  (w_qkv bf16; later reused as wob)
  bf16* qb  = (bf16*)(ws + 256 + 56 * MB);    // 32 MiB  (B,H,T,HD) pre-scaled
  bf16* kb  = (bf16*)(ws + 256 + 88 * MB);    // 32 MiB  (B,H,T,HD)
  bf16* vt  = (bf16*)(ws + 256 + 120 * MB);   // 32 MiB  (B,H,HD,T)
  bf16* yb  = xb;                             // attention output (B,T,D)
  bf16* wob = wqb;                            // w_o bf16 (converted after gemm1)

  convert_to_bf16<<<1024, 256, 0, stream>>>(x_raw, xb, (long)in_sizes[0]);
  convert_to_bf16<<<1024, 256, 0, stream>>>(wq_raw, wqb, (long)in_sizes[2]);

  // qkv projection (M=8192, N=6144, K=2048), scatter to per-head layouts
  gemm256<0><<<dim3(24, 32), 512, 0, stream>>>(xb, wqb, qb, kb, vt, 8192, 6144, 2048);

  // w_o conversion (overwrites wqb region — dead after gemm1)
  convert_to_bf16<<<1024, 256, 0, stream>>>(wo_raw, wob, (long)in_sizes[3]);

  // fused flash attention (writes yb = xb region — x dead after gemm1)
  attn_kernel<<<dim3(64, 16), 256, 0, stream>>>(qb, kb, vt, mask, yb);

  // output projection (M=8192, N=2048, K=2048), fp32 out
  gemm256<1><<<dim3(8, 32), 512, 0, stream>>>(yb, wob, out, nullptr, nullptr, 8192, 2048, 2048);
}